// Round 14
// baseline (333.479 us; speedup 1.0000x reference)
//
#include <hip/hip_runtime.h>
#include <hip/hip_bf16.h>

// TriangleMultiplication on MI355X (gfx950).
// Pipeline: k_prep ; k_proj<0> (leftT) ; k_proj<1> (rightTT) ; k_tri (tri[h][pos]) ;
//           k_trT (tri -> triT[pos][h]) ; k_final v10 (C^T + async LDS staging).
// This round: epilogue LDS-bounce in k_proj/k_tri -> >=128B-contiguous global
// stores (kills ~2x HBM write amplification from 32B scattered segments).
// ws layout: WlT|WrT|WgT|WoT (4*32KB) + leftT/triT (64MB) + rightTT (64MB) + tri (64MB)

#define LSZ 512
#define NPOS (LSZ * LSZ)  // 262144 positions

typedef short s16;
typedef __attribute__((ext_vector_type(4))) short s16x4;
typedef __attribute__((ext_vector_type(8))) short s16x8;
typedef __attribute__((ext_vector_type(4))) float f32x4;

typedef const __attribute__((address_space(1))) unsigned int* gas1;
typedef __attribute__((address_space(3))) unsigned int* las3;

static __device__ __forceinline__ s16 f2bf(float f) {
    unsigned int u = __builtin_bit_cast(unsigned int, f);
    u += 0x7FFFu + ((u >> 16) & 1u);
    return (s16)(u >> 16);
}

// packed RNE fp32->bf16 pair (emits v_cvt_pk_bf16_f32; same bits as f2bf)
static __device__ __forceinline__ unsigned pkbf(float x, float y) {
    __hip_bfloat162 h = __float22bfloat162_rn(make_float2(x, y));
    unsigned u;
    __builtin_memcpy(&u, &h, 4);
    return u;
}
static __device__ __forceinline__ s16x8 cvt8(f32x4 a, f32x4 b) {
    union { s16x8 v; unsigned u[4]; } r;
    r.u[0] = pkbf(a[0], a[1]);
    r.u[1] = pkbf(a[2], a[3]);
    r.u[2] = pkbf(b[0], b[1]);
    r.u[3] = pkbf(b[2], b[3]);
    return r.v;
}
static __device__ __forceinline__ s16x4 cvt4(float x0, float x1, float x2, float x3) {
    union { s16x4 v; unsigned u[2]; } r;
    r.u[0] = pkbf(x0, x1);
    r.u[1] = pkbf(x2, x3);
    return r.v;
}

static __device__ __forceinline__ void gload_lds16(const void* g, void* l) {
    __builtin_amdgcn_global_load_lds((gas1)g, (las3)l, 16, 0, 0);
}

// ---------------- K0: transpose weights to bf16 [out][in] ----------------
__global__ void k_prep(const float* __restrict__ Wl, const float* __restrict__ Wr,
                       const float* __restrict__ Wg, const float* __restrict__ Wo,
                       s16* __restrict__ WlT, s16* __restrict__ WrT,
                       s16* __restrict__ WgT, s16* __restrict__ WoT) {
    const float* src;
    s16* dst;
    switch (blockIdx.x) {
        case 0: src = Wl; dst = WlT; break;
        case 1: src = Wr; dst = WrT; break;
        case 2: src = Wg; dst = WgT; break;
        default: src = Wo; dst = WoT; break;
    }
    for (int e = threadIdx.x; e < 128 * 128; e += blockDim.x) {
        int o = e >> 7, i = e & 127;
        dst[e] = f2bf(src[i * 128 + o]);  // WT[o][i] = W[i][o]
    }
}

// ---------------- K1: projection GEMM, output transposed [h][pos] ----------------
// Epilogue: acc -> As-bounce (stride 130, bank-rotated) -> 128B-contiguous stores.
template <int COLMODE>
__global__ __launch_bounds__(256) void k_proj(const float* __restrict__ pair,
                                              const s16* __restrict__ WT,
                                              const float* __restrict__ bias,
                                              s16* __restrict__ outT) {
    __shared__ __align__(16) s16 As[128 * 130];  // staging uses first 32KB; bounce uses [128][130]
    const int t = threadIdx.x;
    const int b = blockIdx.x;
    const int c0 = b & 511, rb = b >> 9;
    {
        const int p = t >> 1;
        const int dh = (t & 1) << 6;
        long gpos = COLMODE ? ((long)(rb * 128 + p) * 512 + c0) : ((long)b * 128 + p);
        const float* src = pair + gpos * 128 + dh;
        const int swz = (p & 7) << 4;
        char* lrow = (char*)As + p * 256;
#pragma unroll
        for (int g = 0; g < 8; ++g) {
            f32x4 v0 = *(const f32x4*)(src + g * 8);
            f32x4 v1 = *(const f32x4*)(src + g * 8 + 4);
            s16x8 pk = cvt8(v0, v1);
            *(s16x8*)(lrow + ((dh * 2 + g * 16) ^ swz)) = pk;
        }
    }
    __syncthreads();
    const int w = t >> 6, l = t & 63;
    const int wr = (w >> 1) * 64, wc = (w & 1) * 64;
    const int lr = l & 15, lg = l >> 4;
    f32x4 acc[4][4];
#pragma unroll
    for (int mi = 0; mi < 4; ++mi)
#pragma unroll
        for (int ni = 0; ni < 4; ++ni) acc[mi][ni] = (f32x4){0.f, 0.f, 0.f, 0.f};
#pragma unroll
    for (int ks = 0; ks < 4; ++ks) {
        const int kk = ks * 32 + lg * 8;
        s16x8 af[4], bfv[4];
#pragma unroll
        for (int mi = 0; mi < 4; ++mi) {
            int row = wr + mi * 16 + lr;
            af[mi] = *(const s16x8*)((const char*)As + ((row * 256 + kk * 2) ^ ((row & 7) << 4)));
        }
#pragma unroll
        for (int ni = 0; ni < 4; ++ni) {
            int h = wc + ni * 16 + lr;
            bfv[ni] = *(const s16x8*)(WT + h * 128 + kk);
        }
#pragma unroll
        for (int mi = 0; mi < 4; ++mi)
#pragma unroll
            for (int ni = 0; ni < 4; ++ni)
                acc[mi][ni] = __builtin_amdgcn_mfma_f32_16x16x32_bf16(af[mi], bfv[ni], acc[mi][ni], 0, 0, 0);
    }
    // ---- epilogue bounce: [h][pos] tile, stride 130 (bank-rotated) ----
    __syncthreads();  // all MFMA reads of As done before overwrite
#pragma unroll
    for (int ni = 0; ni < 4; ++ni) {
        const int h = wc + ni * 16 + lr;
        const float bv = bias[h];
#pragma unroll
        for (int mi = 0; mi < 4; ++mi) {
            const int p0 = wr + mi * 16 + lg * 4;
            s16x4 pk = cvt4(acc[mi][ni][0] + bv, acc[mi][ni][1] + bv,
                            acc[mi][ni][2] + bv, acc[mi][ni][3] + bv);
            *(s16x4*)(As + h * 130 + p0) = pk;
        }
    }
    __syncthreads();
    // ---- readout: thread t -> h-row t>>1, half t&1 -> 128B contiguous store ----
    {
        const int hh = t >> 1, hf = t & 1;
        const long obase = (long)hh * NPOS +
                           (COLMODE ? ((long)c0 * 512 + rb * 128) : ((long)b * 128)) + hf * 64;
        const s16* src = As + hh * 130 + hf * 64;
#pragma unroll
        for (int j = 0; j < 8; ++j)
            *(s16x8*)(outT + obase + j * 8) = *(const s16x8*)(src + j * 8);
    }
}

// ---------------- K2: triangle einsum = 128 batched 512^3 GEMMs ----------------
// Epilogue: acc -> SH-bounce (stride 130) -> 128B-contiguous stores.
__global__ __launch_bounds__(256) void k_tri(const s16* __restrict__ leftT,
                                             const s16* __restrict__ rightTT,
                                             s16* __restrict__ tri) {
    __shared__ __align__(16) s16 SH[128 * 130];  // GEMM: As=SH[0..8191], Bs=SH[8192..16383]
    s16* As = SH;
    s16* Bs = SH + 128 * 64;
    const int t = threadIdx.x;
    const int logical = ((blockIdx.x & 7) << 8) | (blockIdx.x >> 3);
    const int h = logical >> 4;
    const int ti = (logical >> 2) & 3, tj = logical & 3;
    const s16* Ap = leftT + (long)h * NPOS + ti * 128 * 512;
    const s16* Bp = rightTT + (long)h * NPOS + tj * 128 * 512;
    const int w = t >> 6, l = t & 63;
    const int wr = (w >> 1) * 64, wc = (w & 1) * 64;
    const int lr = l & 15, lg = l >> 4;
    const int srow = t >> 3;
    const int skk = (t & 7) << 3;
    f32x4 acc[4][4];
#pragma unroll
    for (int mi = 0; mi < 4; ++mi)
#pragma unroll
        for (int ni = 0; ni < 4; ++ni) acc[mi][ni] = (f32x4){0.f, 0.f, 0.f, 0.f};
    for (int kb = 0; kb < 512; kb += 64) {
        __syncthreads();
#pragma unroll
        for (int P = 0; P < 4; ++P) {
            int row = P * 32 + srow;
            int kks = skk ^ ((row & 7) << 3);
            unsigned loff = P * 4096 + w * 1024;
            gload_lds16(Ap + row * 512 + kb + kks, (char*)As + loff);
            gload_lds16(Bp + row * 512 + kb + kks, (char*)Bs + loff);
        }
        __syncthreads();
#pragma unroll
        for (int ks = 0; ks < 2; ++ks) {
            const int kk = ks * 32 + lg * 8;
            s16x8 af[4], bfv[4];
#pragma unroll
            for (int mi = 0; mi < 4; ++mi) {
                int row = wr + mi * 16 + lr;
                af[mi] = *(const s16x8*)((const char*)As + ((row * 128 + kk * 2) ^ ((row & 7) << 4)));
            }
#pragma unroll
            for (int ni = 0; ni < 4; ++ni) {
                int row = wc + ni * 16 + lr;
                bfv[ni] = *(const s16x8*)((const char*)Bs + ((row * 128 + kk * 2) ^ ((row & 7) << 4)));
            }
#pragma unroll
            for (int mi = 0; mi < 4; ++mi)
#pragma unroll
                for (int ni = 0; ni < 4; ++ni)
                    acc[mi][ni] = __builtin_amdgcn_mfma_f32_16x16x32_bf16(af[mi], bfv[ni], acc[mi][ni], 0, 0, 0);
        }
    }
    // ---- epilogue bounce: [i][j] tile, stride 130 ----
    __syncthreads();  // all MFMA reads of SH done before overwrite
#pragma unroll
    for (int mi = 0; mi < 4; ++mi)
#pragma unroll
        for (int r = 0; r < 4; ++r) {
            const int il = wr + mi * 16 + lg * 4 + r;
#pragma unroll
            for (int ni = 0; ni < 4; ++ni)
                SH[il * 130 + wc + ni * 16 + lr] = f2bf(acc[mi][ni][r]);
        }
    __syncthreads();
    // ---- readout: thread t -> i-row t>>1, half t&1 -> 128B contiguous store ----
    {
        const int il = t >> 1, hf = t & 1;
        const int gi = ti * 128 + il;
        s16* dst = tri + (long)h * NPOS + (long)gi * 512 + tj * 128 + hf * 64;
        const s16* src = SH + il * 130 + hf * 64;
#pragma unroll
        for (int j = 0; j < 8; ++j)
            *(s16x8*)(dst + j * 8) = *(const s16x8*)(src + j * 8);
    }
}

// ---------------- K2b: transpose tri[h][pos] -> triT[pos][h] ----------------
__global__ __launch_bounds__(256) void k_trT(const s16* __restrict__ tri,
                                             s16* __restrict__ triT) {
    __shared__ __align__(16) s16 Ts[128 * 256];  // 64KB, [h][pos] swizzled
    const int t = threadIdx.x;
    const int w = t >> 6;
    const long posBase = (long)blockIdx.x * 256;
#pragma unroll
    for (int P = 0; P < 16; ++P) {
        const int S = P * 256 + t;
        const int h = S >> 5, u = S & 31;
        const int ug = u ^ ((h >> 3) & 7);
        gload_lds16(tri + (long)h * NPOS + posBase + (ug << 3),
                    (char*)Ts + (P * 256 + w * 64) * 16);
    }
    __syncthreads();
    const int hc = t & 15;
    const int pr = t >> 4;
    const int g = hc & 7;
#pragma unroll
    for (int it = 0; it < 16; ++it) {
        const int p = pr + it * 16;
        const int pu = (p >> 3) ^ g, po = p & 7;
        s16x8 pk;
#pragma unroll
        for (int j = 0; j < 8; ++j)
            pk[j] = Ts[(hc * 8 + j) * 256 + pu * 8 + po];
        *(s16x8*)(triT + (posBase + p) * 128 + hc * 8) = pk;
    }
}

// ---------------- K3 v10: C^T form + async LDS staging (counted vmcnt) ----------------
#define WAITVM(N) asm volatile("s_waitcnt vmcnt(" #N ")" ::: "memory")

#define SUBTILE(BUF, SUB) do {                                                        \
    const int row_ = (SUB) * 16 + lr;                                                 \
    const char* tbp_ = (const char*)&TRI[BUF][0] + row_ * 256;                        \
    const char* pbp_ = (const char*)&PA[BUF][0] + row_ * 512;                         \
    f32x4 accO_ = (f32x4){0.f, 0.f, 0.f, 0.f};                                        \
    f32x4 accG_ = (f32x4){0.f, 0.f, 0.f, 0.f};                                        \
    _Pragma("unroll")                                                                 \
    for (int ks = 0; ks < 4; ++ks) {                                                  \
        s16x8 tbv_ = *(const s16x8*)(tbp_ + ((((ks << 2) | lg) ^ rsw) << 4));         \
        f32x4 pa0_ = *(const f32x4*)(pbp_ + ((((ks << 3) | (lg << 1)) ^ rsw) << 4));  \
        f32x4 pa1_ = *(const f32x4*)(pbp_ + (((((ks << 3) | (lg << 1)) + 1) ^ rsw) << 4)); \
        s16x8 pf_ = cvt8(pa0_, pa1_);                                                 \
        accO_ = __builtin_amdgcn_mfma_f32_16x16x32_bf16(wo[ks], tbv_, accO_, 0, 0, 0);\
        accG_ = __builtin_amdgcn_mfma_f32_16x16x32_bf16(wg[ks], pf_, accG_, 0, 0, 0); \
    }                                                                                 \
    f32x4 rs_ = *(const f32x4*)(pbp_ + ((((w << 2) | lg) ^ rsw) << 4));               \
    f32x4 xr_;                                                                        \
    _Pragma("unroll")                                                                 \
    for (int r = 0; r < 4; ++r) {                                                     \
        const float gate_ = 1.f / (1.f + __expf(-(accG_[r] + bg4[r])));               \
        xr_[r] = rs_[r] + gate_ * (accO_[r] + bo4[r]);                                \
    }                                                                                 \
    *(f32x4*)&xbuf[row_][dl] = xr_;                                                   \
} while (0)

#define LNPASS(P, META) do {                                                          \
    const int row_ = (P) * 16 + (t >> 5);                                             \
    f32x4 xv_ = *(const f32x4*)&xbuf[row_][lnc];                                      \
    float s_ = xv_[0] + xv_[1] + xv_[2] + xv_[3];                                     \
    s_ += __shfl_xor(s_, 1); s_ += __shfl_xor(s_, 2); s_ += __shfl_xor(s_, 4);        \
    s_ += __shfl_xor(s_, 8); s_ += __shfl_xor(s_, 16);                                \
    const float mu_ = s_ * 0.0078125f;                                                \
    float v_ = 0.f;                                                                   \
    _Pragma("unroll")                                                                 \
    for (int j = 0; j < 4; ++j) { float dd_ = xv_[j] - mu_; v_ += dd_ * dd_; }        \
    v_ += __shfl_xor(v_, 1); v_ += __shfl_xor(v_, 2); v_ += __shfl_xor(v_, 4);        \
    v_ += __shfl_xor(v_, 8); v_ += __shfl_xor(v_, 16);                                \
    const float rstd_ = rsqrtf(v_ * 0.0078125f + 1e-5f);                              \
    f32x4 o_;                                                                         \
    _Pragma("unroll")                                                                 \
    for (int j = 0; j < 4; ++j) o_[j] = (xv_[j] - mu_) * rstd_ * gm4[j] + bt4[j];     \
    *(f32x4*)(out + ((META) * 32 + row_) * 128 + lnc) = o_;                           \
} while (0)

#define ITER(M, NLIT, DOPF) do {                                                      \
    WAITVM(NLIT);                                                                     \
    __builtin_amdgcn_s_barrier();                                                     \
    SUBTILE((M) & 1, 0);                                                              \
    SUBTILE((M) & 1, 1);                                                              \
    asm volatile("s_waitcnt lgkmcnt(0)" ::: "memory");                                \
    __builtin_amdgcn_s_barrier();                                                     \
    __builtin_amdgcn_sched_barrier(0);                                                \
    if (DOPF) stage((M) & 1, meta0 + (M) + 2);                                        \
    LNPASS(0, meta0 + (M));                                                           \
    LNPASS(1, meta0 + (M));                                                           \
} while (0)

__global__ __launch_bounds__(512, 2) void k_final(const float* __restrict__ pair,
                                                  const s16* __restrict__ triT,
                                                  const s16* __restrict__ WgT,
                                                  const s16* __restrict__ WoT,
                                                  const float* __restrict__ bgv,
                                                  const float* __restrict__ bov,
                                                  const float* __restrict__ gam,
                                                  const float* __restrict__ bet,
                                                  float* __restrict__ out) {
    __shared__ __align__(16) s16 TRI[2][32 * 128];   // 2 x 8KB  (bf16 [pos][h], swizzled)
    __shared__ __align__(16) float PA[2][32 * 128];  // 2 x 16KB (fp32 [pos][d], swizzled)
    __shared__ __align__(16) float xbuf[32][132];    // 16.9KB
    const int t = threadIdx.x;
    const int w = t >> 6, l = t & 63;
    const int lr = l & 15, lg = l >> 4;
    const int d0 = w << 4;             // wave's d-stripe
    const int dl = d0 + (lg << 2);     // lane's d base (epilogue rows)
    const int rsw = lr & 7;            // read-side swizzle key (row&7; rows = s*16+lr)
    // weights: loaded ONCE, A-operand of both GEMMs (32 VGPRs)
    s16x8 wo[4], wg[4];
#pragma unroll
    for (int ks = 0; ks < 4; ++ks) {
        wo[ks] = *(const s16x8*)(WoT + (d0 + lr) * 128 + ks * 32 + lg * 8);
        wg[ks] = *(const s16x8*)(WgT + (d0 + lr) * 128 + ks * 32 + lg * 8);
    }
    const f32x4 bo4 = *(const f32x4*)(bov + dl);
    const f32x4 bg4 = *(const f32x4*)(bgv + dl);
    const int lnc = (t & 31) << 2;     // LN: d chunk (f32x4)
    const f32x4 gm4 = *(const f32x4*)(gam + lnc);
    const f32x4 bt4 = *(const f32x4*)(bet + lnc);
    const long meta0 = (long)blockIdx.x * 8;

    // stage one 32-pos meta: 3 gload_lds16 per thread, linear LDS dest
    // (wave-uniform base + lane*16), source pre-swizzled by u^=(row&7).
    auto stage = [&](int buf, long meta) {
        const long pb = meta * 32;
        {
            const int row = t >> 4, u = t & 15;  // triT: 16 units x 16B per row
            gload_lds16(triT + (pb + row) * 128 + ((u ^ (row & 7)) << 3),
                        (char*)&TRI[buf][0] + t * 16);
        }
        {
            const int row = t >> 5, u = t & 31;  // pair rows 0..15: 32 units x 16B
            gload_lds16(pair + (pb + row) * 128 + ((u ^ (row & 7)) << 2),
                        (char*)&PA[buf][0] + t * 16);
        }
        {
            const int row = 16 + (t >> 5), u = t & 31;  // pair rows 16..31
            gload_lds16(pair + (pb + row) * 128 + ((u ^ (row & 7)) << 2),
                        (char*)&PA[buf][0] + 8192 + t * 16);
        }
    };

    stage(0, meta0 + 0);
    stage(1, meta0 + 1);
    ITER(0, 3, 1);
    ITER(1, 3, 1);
    ITER(2, 3, 1);
    ITER(3, 3, 1);
    ITER(4, 3, 1);
    ITER(5, 3, 1);
    ITER(6, 3, 0);
    ITER(7, 0, 0);
}

extern "C" void kernel_launch(void* const* d_in, const int* in_sizes, int n_in,
                              void* d_out, int out_size, void* d_ws, size_t ws_size,
                              hipStream_t stream) {
    const float* pair = (const float*)d_in[0];
    const float* Wl   = (const float*)d_in[1];
    const float* bl   = (const float*)d_in[2];
    const float* Wr   = (const float*)d_in[3];
    const float* br   = (const float*)d_in[4];
    const float* Wo   = (const float*)d_in[5];
    const float* bo   = (const float*)d_in[6];
    const float* Wg   = (const float*)d_in[7];
    const float* bg   = (const float*)d_in[8];
    const float* gam  = (const float*)d_in[9];
    const float* bet  = (const float*)d_in[10];
    float* out = (float*)d_out;

    s16* WlT = (s16*)d_ws;
    s16* WrT = WlT + 128 * 128;
    s16* WgT = WrT + 128 * 128;
    s16* WoT = WgT + 128 * 128;
    s16* leftT   = WoT + 128 * 128;            // [128][NPOS]; becomes triT after k_tri
    s16* rightTT = leftT + (long)128 * NPOS;   // [128][NPOS]
    s16* tri     = rightTT + (long)128 * NPOS; // [128][NPOS]
    s16* triT    = leftT;                      // [NPOS][128]

    k_prep<<<4, 256, 0, stream>>>(Wl, Wr, Wg, Wo, WlT, WrT, WgT, WoT);
    k_proj<0><<<2048, 256, 0, stream>>>(pair, WlT, bl, leftT);
    k_proj<1><<<2048, 256, 0, stream>>>(pair, WrT, br, rightTT);
    k_tri<<<2048, 256, 0, stream>>>(leftT, rightTT, tri);
    k_trT<<<1024, 256, 0, stream>>>(tri, triT);
    k_final<<<1024, 512, 0, stream>>>(pair, triT, WgT, WoT, bg, bo, gam, bet, out);
}

// Round 15
// 307.187 us; speedup vs baseline: 1.0856x; 1.0856x over previous
//
#include <hip/hip_runtime.h>
#include <hip/hip_bf16.h>

// TriangleMultiplication on MI355X (gfx950).
// Pipeline: k_prep ; k_proj<0> (leftT) ; k_proj<1> (rightTT) ; k_tri v2 (256^2 tiles) ;
//           k_trT (tri -> triT[pos][h]) ; k_final v10 (C^T + async LDS staging).
// ws layout: WlT|WrT|WgT|WoT (4*32KB) + leftT/triT (64MB) + rightTT (64MB) + tri (64MB)

#define LSZ 512
#define NPOS (LSZ * LSZ)  // 262144 positions

typedef short s16;
typedef __attribute__((ext_vector_type(4))) short s16x4;
typedef __attribute__((ext_vector_type(8))) short s16x8;
typedef __attribute__((ext_vector_type(4))) float f32x4;

typedef const __attribute__((address_space(1))) unsigned int* gas1;
typedef __attribute__((address_space(3))) unsigned int* las3;

static __device__ __forceinline__ s16 f2bf(float f) {
    unsigned int u = __builtin_bit_cast(unsigned int, f);
    u += 0x7FFFu + ((u >> 16) & 1u);
    return (s16)(u >> 16);
}

// packed RNE fp32->bf16 pair (emits v_cvt_pk_bf16_f32; same bits as f2bf)
static __device__ __forceinline__ unsigned pkbf(float x, float y) {
    __hip_bfloat162 h = __float22bfloat162_rn(make_float2(x, y));
    unsigned u;
    __builtin_memcpy(&u, &h, 4);
    return u;
}
static __device__ __forceinline__ s16x8 cvt8(f32x4 a, f32x4 b) {
    union { s16x8 v; unsigned u[4]; } r;
    r.u[0] = pkbf(a[0], a[1]);
    r.u[1] = pkbf(a[2], a[3]);
    r.u[2] = pkbf(b[0], b[1]);
    r.u[3] = pkbf(b[2], b[3]);
    return r.v;
}
static __device__ __forceinline__ s16x4 cvt4(float x0, float x1, float x2, float x3) {
    union { s16x4 v; unsigned u[2]; } r;
    r.u[0] = pkbf(x0, x1);
    r.u[1] = pkbf(x2, x3);
    return r.v;
}

static __device__ __forceinline__ void gload_lds16(const void* g, void* l) {
    __builtin_amdgcn_global_load_lds((gas1)g, (las3)l, 16, 0, 0);
}

// ---------------- K0: transpose weights to bf16 [out][in] ----------------
__global__ void k_prep(const float* __restrict__ Wl, const float* __restrict__ Wr,
                       const float* __restrict__ Wg, const float* __restrict__ Wo,
                       s16* __restrict__ WlT, s16* __restrict__ WrT,
                       s16* __restrict__ WgT, s16* __restrict__ WoT) {
    const float* src;
    s16* dst;
    switch (blockIdx.x) {
        case 0: src = Wl; dst = WlT; break;
        case 1: src = Wr; dst = WrT; break;
        case 2: src = Wg; dst = WgT; break;
        default: src = Wo; dst = WoT; break;
    }
    for (int e = threadIdx.x; e < 128 * 128; e += blockDim.x) {
        int o = e >> 7, i = e & 127;
        dst[e] = f2bf(src[i * 128 + o]);  // WT[o][i] = W[i][o]
    }
}

// ---------------- K1: projection GEMM, output transposed [h][pos] ----------------
template <int COLMODE>
__global__ __launch_bounds__(256) void k_proj(const float* __restrict__ pair,
                                              const s16* __restrict__ WT,
                                              const float* __restrict__ bias,
                                              s16* __restrict__ outT) {
    __shared__ __align__(16) s16 As[128 * 128];  // 32KB, XOR-swizzled rows (256B)
    const int t = threadIdx.x;
    const int b = blockIdx.x;
    const int c0 = b & 511, rb = b >> 9;
    {
        const int p = t >> 1;
        const int dh = (t & 1) << 6;
        long gpos = COLMODE ? ((long)(rb * 128 + p) * 512 + c0) : ((long)b * 128 + p);
        const float* src = pair + gpos * 128 + dh;
        const int swz = (p & 7) << 4;
        char* lrow = (char*)As + p * 256;
#pragma unroll
        for (int g = 0; g < 8; ++g) {
            f32x4 v0 = *(const f32x4*)(src + g * 8);
            f32x4 v1 = *(const f32x4*)(src + g * 8 + 4);
            s16x8 pk = cvt8(v0, v1);
            *(s16x8*)(lrow + ((dh * 2 + g * 16) ^ swz)) = pk;
        }
    }
    __syncthreads();
    const int w = t >> 6, l = t & 63;
    const int wr = (w >> 1) * 64, wc = (w & 1) * 64;
    const int lr = l & 15, lg = l >> 4;
    f32x4 acc[4][4];
#pragma unroll
    for (int mi = 0; mi < 4; ++mi)
#pragma unroll
        for (int ni = 0; ni < 4; ++ni) acc[mi][ni] = (f32x4){0.f, 0.f, 0.f, 0.f};
#pragma unroll
    for (int ks = 0; ks < 4; ++ks) {
        const int kk = ks * 32 + lg * 8;
        s16x8 af[4], bfv[4];
#pragma unroll
        for (int mi = 0; mi < 4; ++mi) {
            int row = wr + mi * 16 + lr;
            af[mi] = *(const s16x8*)((const char*)As + ((row * 256 + kk * 2) ^ ((row & 7) << 4)));
        }
#pragma unroll
        for (int ni = 0; ni < 4; ++ni) {
            int h = wc + ni * 16 + lr;
            bfv[ni] = *(const s16x8*)(WT + h * 128 + kk);
        }
#pragma unroll
        for (int mi = 0; mi < 4; ++mi)
#pragma unroll
            for (int ni = 0; ni < 4; ++ni)
                acc[mi][ni] = __builtin_amdgcn_mfma_f32_16x16x32_bf16(af[mi], bfv[ni], acc[mi][ni], 0, 0, 0);
    }
#pragma unroll
    for (int ni = 0; ni < 4; ++ni) {
        const int h = wc + ni * 16 + lr;
        const float bv = bias[h];
        long base = (long)h * NPOS + (COLMODE ? ((long)c0 * 512 + rb * 128) : ((long)b * 128));
#pragma unroll
        for (int mi = 0; mi < 4; ++mi) {
            const int prow = wr + mi * 16 + lg * 4;
            s16x4 pk = cvt4(acc[mi][ni][0] + bv, acc[mi][ni][1] + bv,
                            acc[mi][ni][2] + bv, acc[mi][ni][3] + bv);
            *(s16x4*)(outT + base + prow) = pk;
        }
    }
}

// ---------------- K2 v2: triangle einsum, 256^2 tiles (halves panel re-reads) ----------------
// 8 waves (2M x 4N), per-wave 128x64 output, BK=64, LDS 64KB, 2 blocks/CU.
__global__ __launch_bounds__(512, 2) void k_tri(const s16* __restrict__ leftT,
                                                const s16* __restrict__ rightTT,
                                                s16* __restrict__ tri) {
    __shared__ __align__(16) s16 As[256 * 64];  // 32KB, u^(row&7) swizzled 16B units
    __shared__ __align__(16) s16 Bs[256 * 64];  // 32KB
    const int t = threadIdx.x;
    // 512 blocks = 128 h x 2 x 2; XCD-bijective (512 % 8 == 0), h-tiles XCD-contiguous
    const int logical = ((blockIdx.x & 7) << 6) | (blockIdx.x >> 3);
    const int h = logical >> 2;
    const int ti = (logical >> 1) & 1, tj = logical & 1;
    const s16* Ap = leftT + (long)h * NPOS + (long)ti * 256 * 512;
    const s16* Bp = rightTT + (long)h * NPOS + (long)tj * 256 * 512;
    const int w = t >> 6, l = t & 63;
    const int wr = (w >> 2) * 128, wc = (w & 3) * 64;
    const int lr = l & 15, lg = l >> 4;
    f32x4 acc[8][4];
#pragma unroll
    for (int mi = 0; mi < 8; ++mi)
#pragma unroll
        for (int ni = 0; ni < 4; ++ni) acc[mi][ni] = (f32x4){0.f, 0.f, 0.f, 0.f};
    for (int kb = 0; kb < 512; kb += 64) {
        __syncthreads();  // prior ds_reads done before DMA overwrite (drains vm+lgkm)
#pragma unroll
        for (int P = 0; P < 4; ++P) {
            const int unit = P * 512 + t;          // 2048 16B units per matrix
            const int row = unit >> 3, u = unit & 7;
            const int kks = (u ^ (row & 7)) << 3;  // pre-swizzled source (involution)
            gload_lds16(Ap + (long)row * 512 + kb + kks, (char*)As + unit * 16);
            gload_lds16(Bp + (long)row * 512 + kb + kks, (char*)Bs + unit * 16);
        }
        __syncthreads();  // DMA landed (vmcnt(0) drained by barrier)
#pragma unroll
        for (int ks = 0; ks < 2; ++ks) {
            s16x8 af[8], bfv[4];
#pragma unroll
            for (int mi = 0; mi < 8; ++mi) {
                const int row = wr + mi * 16 + lr;
                af[mi] = *(const s16x8*)((const char*)As + row * 128 + (((ks * 4 + lg) ^ (row & 7)) << 4));
            }
#pragma unroll
            for (int ni = 0; ni < 4; ++ni) {
                const int row = wc + ni * 16 + lr;
                bfv[ni] = *(const s16x8*)((const char*)Bs + row * 128 + (((ks * 4 + lg) ^ (row & 7)) << 4));
            }
#pragma unroll
            for (int mi = 0; mi < 8; ++mi)
#pragma unroll
                for (int ni = 0; ni < 4; ++ni)
                    acc[mi][ni] = __builtin_amdgcn_mfma_f32_16x16x32_bf16(af[mi], bfv[ni], acc[mi][ni], 0, 0, 0);
        }
    }
#pragma unroll
    for (int mi = 0; mi < 8; ++mi) {
#pragma unroll
        for (int r = 0; r < 4; ++r) {
            const int i = ti * 256 + wr + mi * 16 + lg * 4 + r;
            s16* dst = tri + (long)h * NPOS + (long)i * 512 + tj * 256 + wc;
#pragma unroll
            for (int ni = 0; ni < 4; ++ni) dst[ni * 16 + lr] = f2bf(acc[mi][ni][r]);
        }
    }
}

// ---------------- K2b: transpose tri[h][pos] -> triT[pos][h] ----------------
__global__ __launch_bounds__(256) void k_trT(const s16* __restrict__ tri,
                                             s16* __restrict__ triT) {
    __shared__ __align__(16) s16 Ts[128 * 256];  // 64KB, [h][pos] swizzled
    const int t = threadIdx.x;
    const int w = t >> 6;
    const long posBase = (long)blockIdx.x * 256;
#pragma unroll
    for (int P = 0; P < 16; ++P) {
        const int S = P * 256 + t;
        const int h = S >> 5, u = S & 31;
        const int ug = u ^ ((h >> 3) & 7);
        gload_lds16(tri + (long)h * NPOS + posBase + (ug << 3),
                    (char*)Ts + (P * 256 + w * 64) * 16);
    }
    __syncthreads();
    const int hc = t & 15;
    const int pr = t >> 4;
    const int g = hc & 7;
#pragma unroll
    for (int it = 0; it < 16; ++it) {
        const int p = pr + it * 16;
        const int pu = (p >> 3) ^ g, po = p & 7;
        s16x8 pk;
#pragma unroll
        for (int j = 0; j < 8; ++j)
            pk[j] = Ts[(hc * 8 + j) * 256 + pu * 8 + po];
        *(s16x8*)(triT + (posBase + p) * 128 + hc * 8) = pk;
    }
}

// ---------------- K3 v10: C^T form + async LDS staging (counted vmcnt) ----------------
#define WAITVM(N) asm volatile("s_waitcnt vmcnt(" #N ")" ::: "memory")

#define SUBTILE(BUF, SUB) do {                                                        \
    const int row_ = (SUB) * 16 + lr;                                                 \
    const char* tbp_ = (const char*)&TRI[BUF][0] + row_ * 256;                        \
    const char* pbp_ = (const char*)&PA[BUF][0] + row_ * 512;                         \
    f32x4 accO_ = (f32x4){0.f, 0.f, 0.f, 0.f};                                        \
    f32x4 accG_ = (f32x4){0.f, 0.f, 0.f, 0.f};                                        \
    _Pragma("unroll")                                                                 \
    for (int ks = 0; ks < 4; ++ks) {                                                  \
        s16x8 tbv_ = *(const s16x8*)(tbp_ + ((((ks << 2) | lg) ^ rsw) << 4));         \
        f32x4 pa0_ = *(const f32x4*)(pbp_ + ((((ks << 3) | (lg << 1)) ^ rsw) << 4));  \
        f32x4 pa1_ = *(const f32x4*)(pbp_ + (((((ks << 3) | (lg << 1)) + 1) ^ rsw) << 4)); \
        s16x8 pf_ = cvt8(pa0_, pa1_);                                                 \
        accO_ = __builtin_amdgcn_mfma_f32_16x16x32_bf16(wo[ks], tbv_, accO_, 0, 0, 0);\
        accG_ = __builtin_amdgcn_mfma_f32_16x16x32_bf16(wg[ks], pf_, accG_, 0, 0, 0); \
    }                                                                                 \
    f32x4 rs_ = *(const f32x4*)(pbp_ + ((((w << 2) | lg) ^ rsw) << 4));               \
    f32x4 xr_;                                                                        \
    _Pragma("unroll")                                                                 \
    for (int r = 0; r < 4; ++r) {                                                     \
        const float gate_ = 1.f / (1.f + __expf(-(accG_[r] + bg4[r])));               \
        xr_[r] = rs_[r] + gate_ * (accO_[r] + bo4[r]);                                \
    }                                                                                 \
    *(f32x4*)&xbuf[row_][dl] = xr_;                                                   \
} while (0)

#define LNPASS(P, META) do {                                                          \
    const int row_ = (P) * 16 + (t >> 5);                                             \
    f32x4 xv_ = *(const f32x4*)&xbuf[row_][lnc];                                      \
    float s_ = xv_[0] + xv_[1] + xv_[2] + xv_[3];                                     \
    s_ += __shfl_xor(s_, 1); s_ += __shfl_xor(s_, 2); s_ += __shfl_xor(s_, 4);        \
    s_ += __shfl_xor(s_, 8); s_ += __shfl_xor(s_, 16);                                \
    const float mu_ = s_ * 0.0078125f;                                                \
    float v_ = 0.f;                                                                   \
    _Pragma("unroll")                                                                 \
    for (int j = 0; j < 4; ++j) { float dd_ = xv_[j] - mu_; v_ += dd_ * dd_; }        \
    v_ += __shfl_xor(v_, 1); v_ += __shfl_xor(v_, 2); v_ += __shfl_xor(v_, 4);        \
    v_ += __shfl_xor(v_, 8); v_ += __shfl_xor(v_, 16);                                \
    const float rstd_ = rsqrtf(v_ * 0.0078125f + 1e-5f);                              \
    f32x4 o_;                                                                         \
    _Pragma("unroll")                                                                 \
    for (int j = 0; j < 4; ++j) o_[j] = (xv_[j] - mu_) * rstd_ * gm4[j] + bt4[j];     \
    *(f32x4*)(out + ((META) * 32 + row_) * 128 + lnc) = o_;                           \
} while (0)

#define ITER(M, NLIT, DOPF) do {                                                      \
    WAITVM(NLIT);                                                                     \
    __builtin_amdgcn_s_barrier();                                                     \
    SUBTILE((M) & 1, 0);                                                              \
    SUBTILE((M) & 1, 1);                                                              \
    asm volatile("s_waitcnt lgkmcnt(0)" ::: "memory");                                \
    __builtin_amdgcn_s_barrier();                                                     \
    __builtin_amdgcn_sched_barrier(0);                                                \
    if (DOPF) stage((M) & 1, meta0 + (M) + 2);                                        \
    LNPASS(0, meta0 + (M));                                                           \
    LNPASS(1, meta0 + (M));                                                           \
} while (0)

__global__ __launch_bounds__(512, 2) void k_final(const float* __restrict__ pair,
                                                  const s16* __restrict__ triT,
                                                  const s16* __restrict__ WgT,
                                                  const s16* __restrict__ WoT,
                                                  const float* __restrict__ bgv,
                                                  const float* __restrict__ bov,
                                                  const float* __restrict__ gam,
                                                  const float* __restrict__ bet,
                                                  float* __restrict__ out) {
    __shared__ __align__(16) s16 TRI[2][32 * 128];   // 2 x 8KB  (bf16 [pos][h], swizzled)
    __shared__ __align__(16) float PA[2][32 * 128];  // 2 x 16KB (fp32 [pos][d], swizzled)
    __shared__ __align__(16) float xbuf[32][132];    // 16.9KB
    const int t = threadIdx.x;
    const int w = t >> 6, l = t & 63;
    const int lr = l & 15, lg = l >> 4;
    const int d0 = w << 4;             // wave's d-stripe
    const int dl = d0 + (lg << 2);     // lane's d base (epilogue rows)
    const int rsw = lr & 7;            // read-side swizzle key (row&7; rows = s*16+lr)
    // weights: loaded ONCE, A-operand of both GEMMs (32 VGPRs)
    s16x8 wo[4], wg[4];
#pragma unroll
    for (int ks = 0; ks < 4; ++ks) {
        wo[ks] = *(const s16x8*)(WoT + (d0 + lr) * 128 + ks * 32 + lg * 8);
        wg[ks] = *(const s16x8*)(WgT + (d0 + lr) * 128 + ks * 32 + lg * 8);
    }
    const f32x4 bo4 = *(const f32x4*)(bov + dl);
    const f32x4 bg4 = *(const f32x4*)(bgv + dl);
    const int lnc = (t & 31) << 2;     // LN: d chunk (f32x4)
    const f32x4 gm4 = *(const f32x4*)(gam + lnc);
    const f32x4 bt4 = *(const f32x4*)(bet + lnc);
    const long meta0 = (long)blockIdx.x * 8;

    // stage one 32-pos meta: 3 gload_lds16 per thread, linear LDS dest
    // (wave-uniform base + lane*16), source pre-swizzled by u^=(row&7).
    auto stage = [&](int buf, long meta) {
        const long pb = meta * 32;
        {
            const int row = t >> 4, u = t & 15;  // triT: 16 units x 16B per row
            gload_lds16(triT + (pb + row) * 128 + ((u ^ (row & 7)) << 3),
                        (char*)&TRI[buf][0] + t * 16);
        }
        {
            const int row = t >> 5, u = t & 31;  // pair rows 0..15: 32 units x 16B
            gload_lds16(pair + (pb + row) * 128 + ((u ^ (row & 7)) << 2),
                        (char*)&PA[buf][0] + t * 16);
        }
        {
            const int row = 16 + (t >> 5), u = t & 31;  // pair rows 16..31
            gload_lds16(pair + (pb + row) * 128 + ((u ^ (row & 7)) << 2),
                        (char*)&PA[buf][0] + 8192 + t * 16);
        }
    };

    stage(0, meta0 + 0);
    stage(1, meta0 + 1);
    ITER(0, 3, 1);
    ITER(1, 3, 1);
    ITER(2, 3, 1);
    ITER(3, 3, 1);
    ITER(4, 3, 1);
    ITER(5, 3, 1);
    ITER(6, 3, 0);
    ITER(7, 0, 0);
}

extern "C" void kernel_launch(void* const* d_in, const int* in_sizes, int n_in,
                              void* d_out, int out_size, void* d_ws, size_t ws_size,
                              hipStream_t stream) {
    const float* pair = (const float*)d_in[0];
    const float* Wl   = (const float*)d_in[1];
    const float* bl   = (const float*)d_in[2];
    const float* Wr   = (const float*)d_in[3];
    const float* br   = (const float*)d_in[4];
    const float* Wo   = (const float*)d_in[5];
    const float* bo   = (const float*)d_in[6];
    const float* Wg   = (const float*)d_in[7];
    const float* bg   = (const float*)d_in[8];
    const float* gam  = (const float*)d_in[9];
    const float* bet  = (const float*)d_in[10];
    float* out = (float*)d_out;

    s16* WlT = (s16*)d_ws;
    s16* WrT = WlT + 128 * 128;
    s16* WgT = WrT + 128 * 128;
    s16* WoT = WgT + 128 * 128;
    s16* leftT   = WoT + 128 * 128;            // [128][NPOS]; becomes triT after k_tri
    s16* rightTT = leftT + (long)128 * NPOS;   // [128][NPOS]
    s16* tri     = rightTT + (long)128 * NPOS; // [128][NPOS]
    s16* triT    = leftT;                      // [NPOS][128]

    k_prep<<<4, 256, 0, stream>>>(Wl, Wr, Wg, Wo, WlT, WrT, WgT, WoT);
    k_proj<0><<<2048, 256, 0, stream>>>(pair, WlT, bl, leftT);
    k_proj<1><<<2048, 256, 0, stream>>>(pair, WrT, br, rightTT);
    k_tri<<<512, 512, 0, stream>>>(leftT, rightTT, tri);
    k_trT<<<1024, 256, 0, stream>>>(tri, triT);
    k_final<<<1024, 512, 0, stream>>>(pair, triT, WgT, WoT, bg, bo, gam, bet, out);
}

// Round 16
// 281.373 us; speedup vs baseline: 1.1852x; 1.0917x over previous
//
#include <hip/hip_runtime.h>
#include <hip/hip_bf16.h>

// TriangleMultiplication on MI355X (gfx950).
// Pipeline: k_prep ; k_proj<0> (leftT) ; k_proj<1> (rightTT) ; k_tri v2 (256^2 tiles) ;
//           k_final v11 (C^T + async LDS staging; reads tri[h][pos] directly and
//           transposes in LDS via XOR-swizzled scalar gather -- k_trT eliminated).
// ws layout: WlT|WrT|WgT|WoT (4*32KB) + leftT (64MB, dead after k_tri) + rightTT (64MB) + tri (64MB)

#define LSZ 512
#define NPOS (LSZ * LSZ)  // 262144 positions

typedef short s16;
typedef __attribute__((ext_vector_type(4))) short s16x4;
typedef __attribute__((ext_vector_type(8))) short s16x8;
typedef __attribute__((ext_vector_type(4))) float f32x4;

typedef const __attribute__((address_space(1))) unsigned int* gas1;
typedef __attribute__((address_space(3))) unsigned int* las3;

static __device__ __forceinline__ s16 f2bf(float f) {
    unsigned int u = __builtin_bit_cast(unsigned int, f);
    u += 0x7FFFu + ((u >> 16) & 1u);
    return (s16)(u >> 16);
}

// packed RNE fp32->bf16 pair (emits v_cvt_pk_bf16_f32; same bits as f2bf)
static __device__ __forceinline__ unsigned pkbf(float x, float y) {
    __hip_bfloat162 h = __float22bfloat162_rn(make_float2(x, y));
    unsigned u;
    __builtin_memcpy(&u, &h, 4);
    return u;
}
static __device__ __forceinline__ s16x8 cvt8(f32x4 a, f32x4 b) {
    union { s16x8 v; unsigned u[4]; } r;
    r.u[0] = pkbf(a[0], a[1]);
    r.u[1] = pkbf(a[2], a[3]);
    r.u[2] = pkbf(b[0], b[1]);
    r.u[3] = pkbf(b[2], b[3]);
    return r.v;
}
static __device__ __forceinline__ s16x4 cvt4(float x0, float x1, float x2, float x3) {
    union { s16x4 v; unsigned u[2]; } r;
    r.u[0] = pkbf(x0, x1);
    r.u[1] = pkbf(x2, x3);
    return r.v;
}

static __device__ __forceinline__ void gload_lds16(const void* g, void* l) {
    __builtin_amdgcn_global_load_lds((gas1)g, (las3)l, 16, 0, 0);
}

// ---------------- K0: transpose weights to bf16 [out][in] ----------------
__global__ void k_prep(const float* __restrict__ Wl, const float* __restrict__ Wr,
                       const float* __restrict__ Wg, const float* __restrict__ Wo,
                       s16* __restrict__ WlT, s16* __restrict__ WrT,
                       s16* __restrict__ WgT, s16* __restrict__ WoT) {
    const float* src;
    s16* dst;
    switch (blockIdx.x) {
        case 0: src = Wl; dst = WlT; break;
        case 1: src = Wr; dst = WrT; break;
        case 2: src = Wg; dst = WgT; break;
        default: src = Wo; dst = WoT; break;
    }
    for (int e = threadIdx.x; e < 128 * 128; e += blockDim.x) {
        int o = e >> 7, i = e & 127;
        dst[e] = f2bf(src[i * 128 + o]);  // WT[o][i] = W[i][o]
    }
}

// ---------------- K1: projection GEMM, output transposed [h][pos] ----------------
template <int COLMODE>
__global__ __launch_bounds__(256) void k_proj(const float* __restrict__ pair,
                                              const s16* __restrict__ WT,
                                              const float* __restrict__ bias,
                                              s16* __restrict__ outT) {
    __shared__ __align__(16) s16 As[128 * 128];  // 32KB, XOR-swizzled rows (256B)
    const int t = threadIdx.x;
    const int b = blockIdx.x;
    const int c0 = b & 511, rb = b >> 9;
    {
        const int p = t >> 1;
        const int dh = (t & 1) << 6;
        long gpos = COLMODE ? ((long)(rb * 128 + p) * 512 + c0) : ((long)b * 128 + p);
        const float* src = pair + gpos * 128 + dh;
        const int swz = (p & 7) << 4;
        char* lrow = (char*)As + p * 256;
#pragma unroll
        for (int g = 0; g < 8; ++g) {
            f32x4 v0 = *(const f32x4*)(src + g * 8);
            f32x4 v1 = *(const f32x4*)(src + g * 8 + 4);
            s16x8 pk = cvt8(v0, v1);
            *(s16x8*)(lrow + ((dh * 2 + g * 16) ^ swz)) = pk;
        }
    }
    __syncthreads();
    const int w = t >> 6, l = t & 63;
    const int wr = (w >> 1) * 64, wc = (w & 1) * 64;
    const int lr = l & 15, lg = l >> 4;
    f32x4 acc[4][4];
#pragma unroll
    for (int mi = 0; mi < 4; ++mi)
#pragma unroll
        for (int ni = 0; ni < 4; ++ni) acc[mi][ni] = (f32x4){0.f, 0.f, 0.f, 0.f};
#pragma unroll
    for (int ks = 0; ks < 4; ++ks) {
        const int kk = ks * 32 + lg * 8;
        s16x8 af[4], bfv[4];
#pragma unroll
        for (int mi = 0; mi < 4; ++mi) {
            int row = wr + mi * 16 + lr;
            af[mi] = *(const s16x8*)((const char*)As + ((row * 256 + kk * 2) ^ ((row & 7) << 4)));
        }
#pragma unroll
        for (int ni = 0; ni < 4; ++ni) {
            int h = wc + ni * 16 + lr;
            bfv[ni] = *(const s16x8*)(WT + h * 128 + kk);
        }
#pragma unroll
        for (int mi = 0; mi < 4; ++mi)
#pragma unroll
            for (int ni = 0; ni < 4; ++ni)
                acc[mi][ni] = __builtin_amdgcn_mfma_f32_16x16x32_bf16(af[mi], bfv[ni], acc[mi][ni], 0, 0, 0);
    }
#pragma unroll
    for (int ni = 0; ni < 4; ++ni) {
        const int h = wc + ni * 16 + lr;
        const float bv = bias[h];
        long base = (long)h * NPOS + (COLMODE ? ((long)c0 * 512 + rb * 128) : ((long)b * 128));
#pragma unroll
        for (int mi = 0; mi < 4; ++mi) {
            const int prow = wr + mi * 16 + lg * 4;
            s16x4 pk = cvt4(acc[mi][ni][0] + bv, acc[mi][ni][1] + bv,
                            acc[mi][ni][2] + bv, acc[mi][ni][3] + bv);
            *(s16x4*)(outT + base + prow) = pk;
        }
    }
}

// ---------------- K2 v2: triangle einsum, 256^2 tiles ----------------
// 8 waves (2M x 4N), per-wave 128x64 output, BK=64, LDS 64KB, 2 blocks/CU.
__global__ __launch_bounds__(512, 2) void k_tri(const s16* __restrict__ leftT,
                                                const s16* __restrict__ rightTT,
                                                s16* __restrict__ tri) {
    __shared__ __align__(16) s16 As[256 * 64];  // 32KB, u^(row&7) swizzled 16B units
    __shared__ __align__(16) s16 Bs[256 * 64];  // 32KB
    const int t = threadIdx.x;
    // 512 blocks = 128 h x 2 x 2; XCD-bijective (512 % 8 == 0), h-tiles XCD-contiguous
    const int logical = ((blockIdx.x & 7) << 6) | (blockIdx.x >> 3);
    const int h = logical >> 2;
    const int ti = (logical >> 1) & 1, tj = logical & 1;
    const s16* Ap = leftT + (long)h * NPOS + (long)ti * 256 * 512;
    const s16* Bp = rightTT + (long)h * NPOS + (long)tj * 256 * 512;
    const int w = t >> 6, l = t & 63;
    const int wr = (w >> 2) * 128, wc = (w & 3) * 64;
    const int lr = l & 15, lg = l >> 4;
    f32x4 acc[8][4];
#pragma unroll
    for (int mi = 0; mi < 8; ++mi)
#pragma unroll
        for (int ni = 0; ni < 4; ++ni) acc[mi][ni] = (f32x4){0.f, 0.f, 0.f, 0.f};
    for (int kb = 0; kb < 512; kb += 64) {
        __syncthreads();  // prior ds_reads done before DMA overwrite
#pragma unroll
        for (int P = 0; P < 4; ++P) {
            const int unit = P * 512 + t;          // 2048 16B units per matrix
            const int row = unit >> 3, u = unit & 7;
            const int kks = (u ^ (row & 7)) << 3;  // pre-swizzled source (involution)
            gload_lds16(Ap + (long)row * 512 + kb + kks, (char*)As + unit * 16);
            gload_lds16(Bp + (long)row * 512 + kb + kks, (char*)Bs + unit * 16);
        }
        __syncthreads();  // DMA landed
#pragma unroll
        for (int ks = 0; ks < 2; ++ks) {
            s16x8 af[8], bfv[4];
#pragma unroll
            for (int mi = 0; mi < 8; ++mi) {
                const int row = wr + mi * 16 + lr;
                af[mi] = *(const s16x8*)((const char*)As + row * 128 + (((ks * 4 + lg) ^ (row & 7)) << 4));
            }
#pragma unroll
            for (int ni = 0; ni < 4; ++ni) {
                const int row = wc + ni * 16 + lr;
                bfv[ni] = *(const s16x8*)((const char*)Bs + row * 128 + (((ks * 4 + lg) ^ (row & 7)) << 4));
            }
#pragma unroll
            for (int mi = 0; mi < 8; ++mi)
#pragma unroll
                for (int ni = 0; ni < 4; ++ni)
                    acc[mi][ni] = __builtin_amdgcn_mfma_f32_16x16x32_bf16(af[mi], bfv[ni], acc[mi][ni], 0, 0, 0);
        }
    }
#pragma unroll
    for (int mi = 0; mi < 8; ++mi) {
#pragma unroll
        for (int r = 0; r < 4; ++r) {
            const int i = ti * 256 + wr + mi * 16 + lg * 4 + r;
            s16* dst = tri + (long)h * NPOS + (long)i * 512 + tj * 256 + wc;
#pragma unroll
            for (int ni = 0; ni < 4; ++ni) dst[ni * 16 + lr] = f2bf(acc[mi][ni][r]);
        }
    }
}

// ---------------- K3 v11: C^T form + async LDS staging; in-LDS transpose of tri ----------------
// TRI slot layout: slot s holds tri[h = s>>2][pb + po*8 .. +8] with po = (s&3) ^ ((h>>3)&3).
// The XOR key equals lg for the B-frag gather -> 4-way banks instead of 8-way.
#define WAITVM(N) asm volatile("s_waitcnt vmcnt(" #N ")" ::: "memory")

#define SUBTILE(BUF, SUB) do {                                                        \
    const int row_ = (SUB) * 16 + lr;                                                 \
    const int po_ = row_ >> 3, p3_ = row_ & 7;                                        \
    const char* pbp_ = (const char*)&PA[BUF][0] + row_ * 512;                         \
    f32x4 accO_ = (f32x4){0.f, 0.f, 0.f, 0.f};                                        \
    f32x4 accG_ = (f32x4){0.f, 0.f, 0.f, 0.f};                                        \
    _Pragma("unroll")                                                                 \
    for (int ks = 0; ks < 4; ++ks) {                                                  \
        const int kk = ks * 32 + lg * 8;                                              \
        s16x8 tbv_;                                                                   \
        _Pragma("unroll")                                                             \
        for (int j = 0; j < 8; ++j) {                                                 \
            const int hh_ = kk + j;                                                   \
            tbv_[j] = TRI[BUF][(hh_ * 4 + (po_ ^ ((hh_ >> 3) & 3))) * 8 + p3_];       \
        }                                                                             \
        f32x4 pa0_ = *(const f32x4*)(pbp_ + ((((ks << 3) | (lg << 1)) ^ rsw) << 4));  \
        f32x4 pa1_ = *(const f32x4*)(pbp_ + (((((ks << 3) | (lg << 1)) + 1) ^ rsw) << 4)); \
        s16x8 pf_ = cvt8(pa0_, pa1_);                                                 \
        accO_ = __builtin_amdgcn_mfma_f32_16x16x32_bf16(wo[ks], tbv_, accO_, 0, 0, 0);\
        accG_ = __builtin_amdgcn_mfma_f32_16x16x32_bf16(wg[ks], pf_, accG_, 0, 0, 0); \
    }                                                                                 \
    f32x4 rs_ = *(const f32x4*)(pbp_ + ((((w << 2) | lg) ^ rsw) << 4));               \
    f32x4 xr_;                                                                        \
    _Pragma("unroll")                                                                 \
    for (int r = 0; r < 4; ++r) {                                                     \
        const float gate_ = 1.f / (1.f + __expf(-(accG_[r] + bg4[r])));               \
        xr_[r] = rs_[r] + gate_ * (accO_[r] + bo4[r]);                                \
    }                                                                                 \
    *(f32x4*)&xbuf[row_][dl] = xr_;                                                   \
} while (0)

#define LNPASS(P, META) do {                                                          \
    const int row_ = (P) * 16 + (t >> 5);                                             \
    f32x4 xv_ = *(const f32x4*)&xbuf[row_][lnc];                                      \
    float s_ = xv_[0] + xv_[1] + xv_[2] + xv_[3];                                     \
    s_ += __shfl_xor(s_, 1); s_ += __shfl_xor(s_, 2); s_ += __shfl_xor(s_, 4);        \
    s_ += __shfl_xor(s_, 8); s_ += __shfl_xor(s_, 16);                                \
    const float mu_ = s_ * 0.0078125f;                                                \
    float v_ = 0.f;                                                                   \
    _Pragma("unroll")                                                                 \
    for (int j = 0; j < 4; ++j) { float dd_ = xv_[j] - mu_; v_ += dd_ * dd_; }        \
    v_ += __shfl_xor(v_, 1); v_ += __shfl_xor(v_, 2); v_ += __shfl_xor(v_, 4);        \
    v_ += __shfl_xor(v_, 8); v_ += __shfl_xor(v_, 16);                                \
    const float rstd_ = rsqrtf(v_ * 0.0078125f + 1e-5f);                              \
    f32x4 o_;                                                                         \
    _Pragma("unroll")                                                                 \
    for (int j = 0; j < 4; ++j) o_[j] = (xv_[j] - mu_) * rstd_ * gm4[j] + bt4[j];     \
    *(f32x4*)(out + ((META) * 32 + row_) * 128 + lnc) = o_;                           \
} while (0)

#define ITER(M, NLIT, DOPF) do {                                                      \
    WAITVM(NLIT);                                                                     \
    __builtin_amdgcn_s_barrier();                                                     \
    SUBTILE((M) & 1, 0);                                                              \
    SUBTILE((M) & 1, 1);                                                              \
    asm volatile("s_waitcnt lgkmcnt(0)" ::: "memory");                                \
    __builtin_amdgcn_s_barrier();                                                     \
    __builtin_amdgcn_sched_barrier(0);                                                \
    if (DOPF) stage((M) & 1, meta0 + (M) + 2);                                        \
    LNPASS(0, meta0 + (M));                                                           \
    LNPASS(1, meta0 + (M));                                                           \
} while (0)

__global__ __launch_bounds__(512, 2) void k_final(const float* __restrict__ pair,
                                                  const s16* __restrict__ tri,
                                                  const s16* __restrict__ WgT,
                                                  const s16* __restrict__ WoT,
                                                  const float* __restrict__ bgv,
                                                  const float* __restrict__ bov,
                                                  const float* __restrict__ gam,
                                                  const float* __restrict__ bet,
                                                  float* __restrict__ out) {
    __shared__ __align__(16) s16 TRI[2][32 * 128];   // 2 x 8KB  (bf16, slot layout above)
    __shared__ __align__(16) float PA[2][32 * 128];  // 2 x 16KB (fp32 [pos][d], swizzled)
    __shared__ __align__(16) float xbuf[32][132];    // 16.9KB
    const int t = threadIdx.x;
    const int w = t >> 6, l = t & 63;
    const int lr = l & 15, lg = l >> 4;
    const int d0 = w << 4;             // wave's d-stripe
    const int dl = d0 + (lg << 2);     // lane's d base (epilogue rows)
    const int rsw = lr & 7;            // read-side swizzle key for PA
    // weights: loaded ONCE, A-operand of both GEMMs (32 VGPRs)
    s16x8 wo[4], wg[4];
#pragma unroll
    for (int ks = 0; ks < 4; ++ks) {
        wo[ks] = *(const s16x8*)(WoT + (d0 + lr) * 128 + ks * 32 + lg * 8);
        wg[ks] = *(const s16x8*)(WgT + (d0 + lr) * 128 + ks * 32 + lg * 8);
    }
    const f32x4 bo4 = *(const f32x4*)(bov + dl);
    const f32x4 bg4 = *(const f32x4*)(bgv + dl);
    const int lnc = (t & 31) << 2;     // LN: d chunk (f32x4)
    const f32x4 gm4 = *(const f32x4*)(gam + lnc);
    const f32x4 bt4 = *(const f32x4*)(bet + lnc);
    const long meta0 = (long)blockIdx.x * 8;

    // stage one 32-pos meta: 3 gload_lds16 per thread, linear LDS dest.
    // TRI: thread t owns slot t; fetches tri[h=t>>2][pb + po*8] with
    // po = (t&3)^((h>>3)&3) (involution -> gather reads land linearly).
    // PA: 16B units pre-swizzled by u^(row&7).
    auto stage = [&](int buf, long meta) {
        const long pb = meta * 32;
        {
            const int hh = t >> 2;
            const int po = (t & 3) ^ ((hh >> 3) & 3);
            gload_lds16(tri + (long)hh * NPOS + pb + po * 8,
                        (char*)&TRI[buf][0] + t * 16);
        }
        {
            const int row = t >> 5, u = t & 31;  // pair rows 0..15: 32 units x 16B
            gload_lds16(pair + (pb + row) * 128 + ((u ^ (row & 7)) << 2),
                        (char*)&PA[buf][0] + t * 16);
        }
        {
            const int row = 16 + (t >> 5), u = t & 31;  // pair rows 16..31
            gload_lds16(pair + (pb + row) * 128 + ((u ^ (row & 7)) << 2),
                        (char*)&PA[buf][0] + 8192 + t * 16);
        }
    };

    stage(0, meta0 + 0);
    stage(1, meta0 + 1);
    ITER(0, 3, 1);
    ITER(1, 3, 1);
    ITER(2, 3, 1);
    ITER(3, 3, 1);
    ITER(4, 3, 1);
    ITER(5, 3, 1);
    ITER(6, 3, 0);
    ITER(7, 0, 0);
}

extern "C" void kernel_launch(void* const* d_in, const int* in_sizes, int n_in,
                              void* d_out, int out_size, void* d_ws, size_t ws_size,
                              hipStream_t stream) {
    const float* pair = (const float*)d_in[0];
    const float* Wl   = (const float*)d_in[1];
    const float* bl   = (const float*)d_in[2];
    const float* Wr   = (const float*)d_in[3];
    const float* br   = (const float*)d_in[4];
    const float* Wo   = (const float*)d_in[5];
    const float* bo   = (const float*)d_in[6];
    const float* Wg   = (const float*)d_in[7];
    const float* bg   = (const float*)d_in[8];
    const float* gam  = (const float*)d_in[9];
    const float* bet  = (const float*)d_in[10];
    float* out = (float*)d_out;

    s16* WlT = (s16*)d_ws;
    s16* WrT = WlT + 128 * 128;
    s16* WgT = WrT + 128 * 128;
    s16* WoT = WgT + 128 * 128;
    s16* leftT   = WoT + 128 * 128;            // [128][NPOS] (dead after k_tri)
    s16* rightTT = leftT + (long)128 * NPOS;   // [128][NPOS]
    s16* tri     = rightTT + (long)128 * NPOS; // [128][NPOS]

    k_prep<<<4, 256, 0, stream>>>(Wl, Wr, Wg, Wo, WlT, WrT, WgT, WoT);
    k_proj<0><<<2048, 256, 0, stream>>>(pair, WlT, bl, leftT);
    k_proj<1><<<2048, 256, 0, stream>>>(pair, WrT, br, rightTT);
    k_tri<<<512, 512, 0, stream>>>(leftT, rightTT, tri);
    k_final<<<1024, 512, 0, stream>>>(pair, tri, WgT, WoT, bg, bo, gam, bet, out);
}

// Round 17
// 254.557 us; speedup vs baseline: 1.3100x; 1.1053x over previous
//
#include <hip/hip_runtime.h>
#include <hip/hip_bf16.h>

// TriangleMultiplication on MI355X (gfx950).
// Pipeline: k_prep ; k_proj v2 (C^T + async staging, both modes) ; k_tri v2 (256^2) ;
//           k_final v11 (C^T + async staging, in-LDS transpose of tri).
// ws layout: WlT|WrT|WgT|WoT (4*32KB) + leftT (64MB) + rightTT (64MB) + tri (64MB)

#define LSZ 512
#define NPOS (LSZ * LSZ)  // 262144 positions

typedef short s16;
typedef __attribute__((ext_vector_type(4))) short s16x4;
typedef __attribute__((ext_vector_type(8))) short s16x8;
typedef __attribute__((ext_vector_type(4))) float f32x4;

typedef const __attribute__((address_space(1))) unsigned int* gas1;
typedef __attribute__((address_space(3))) unsigned int* las3;

static __device__ __forceinline__ s16 f2bf(float f) {
    unsigned int u = __builtin_bit_cast(unsigned int, f);
    u += 0x7FFFu + ((u >> 16) & 1u);
    return (s16)(u >> 16);
}

// packed RNE fp32->bf16 pair (emits v_cvt_pk_bf16_f32; same bits as f2bf)
static __device__ __forceinline__ unsigned pkbf(float x, float y) {
    __hip_bfloat162 h = __float22bfloat162_rn(make_float2(x, y));
    unsigned u;
    __builtin_memcpy(&u, &h, 4);
    return u;
}
static __device__ __forceinline__ s16x8 cvt8(f32x4 a, f32x4 b) {
    union { s16x8 v; unsigned u[4]; } r;
    r.u[0] = pkbf(a[0], a[1]);
    r.u[1] = pkbf(a[2], a[3]);
    r.u[2] = pkbf(b[0], b[1]);
    r.u[3] = pkbf(b[2], b[3]);
    return r.v;
}
static __device__ __forceinline__ s16x4 cvt4(float x0, float x1, float x2, float x3) {
    union { s16x4 v; unsigned u[2]; } r;
    r.u[0] = pkbf(x0, x1);
    r.u[1] = pkbf(x2, x3);
    return r.v;
}

static __device__ __forceinline__ void gload_lds16(const void* g, void* l) {
    __builtin_amdgcn_global_load_lds((gas1)g, (las3)l, 16, 0, 0);
}

#define WAITVM(N) asm volatile("s_waitcnt vmcnt(" #N ")" ::: "memory")

// ---------------- K0: transpose weights to bf16 [out][in] ----------------
__global__ void k_prep(const float* __restrict__ Wl, const float* __restrict__ Wr,
                       const float* __restrict__ Wg, const float* __restrict__ Wo,
                       s16* __restrict__ WlT, s16* __restrict__ WrT,
                       s16* __restrict__ WgT, s16* __restrict__ WoT) {
    const float* src;
    s16* dst;
    switch (blockIdx.x) {
        case 0: src = Wl; dst = WlT; break;
        case 1: src = Wr; dst = WrT; break;
        case 2: src = Wg; dst = WgT; break;
        default: src = Wo; dst = WoT; break;
    }
    for (int e = threadIdx.x; e < 128 * 128; e += blockDim.x) {
        int o = e >> 7, i = e & 127;
        dst[e] = f2bf(src[i * 128 + o]);  // WT[o][i] = W[i][o]
    }
}

// ---------------- K1 v2: projection GEMM, C^T form + async LDS staging ----------------
// Wave w owns h-stripe [16w,16w+16); weight A-frags resident in 16 VGPRs.
// Meta = 32 pos; PA double-buffered fp32 (2x16KB), gload_lds16 with u^(row&7)
// involution (source pre-swizzle + swizzled read). Counted vmcnt 2,...,2,0.
// COLMODE=0: meta m -> linear pos m*32 (leftT). COLMODE=1: m -> (c0=m>>4,
// r0=(m&15)*32), pos' = c0*512 + r0 + row (rightTT layout).
#define PSUB(BUF, SUB, META) do {                                                     \
    const int row_ = (SUB) * 16 + lr;                                                 \
    const char* pbp_ = (const char*)&PA[BUF][0] + row_ * 512;                         \
    f32x4 acc_ = (f32x4){0.f, 0.f, 0.f, 0.f};                                         \
    _Pragma("unroll")                                                                 \
    for (int ks = 0; ks < 4; ++ks) {                                                  \
        f32x4 pa0_ = *(const f32x4*)(pbp_ + ((((ks << 3) | (lg << 1)) ^ rsw) << 4));  \
        f32x4 pa1_ = *(const f32x4*)(pbp_ + (((((ks << 3) | (lg << 1)) + 1) ^ rsw) << 4)); \
        s16x8 pf_ = cvt8(pa0_, pa1_);                                                 \
        acc_ = __builtin_amdgcn_mfma_f32_16x16x32_bf16(wv[ks], pf_, acc_, 0, 0, 0);   \
    }                                                                                 \
    const long pbase_ = COLMODE ? ((long)((META) >> 4) * 512 + (((META) & 15) << 5) + row_) \
                                : ((long)(META) * 32 + row_);                         \
    _Pragma("unroll")                                                                 \
    for (int r = 0; r < 4; ++r)                                                       \
        outT[(long)(dl + r) * NPOS + pbase_] = f2bf(acc_[r] + b4[r]);                 \
} while (0)

#define PITER(M, NLIT, DOPF) do {                                                     \
    WAITVM(NLIT);                                                                     \
    __builtin_amdgcn_s_barrier();                                                     \
    PSUB((M) & 1, 0, meta0 + (M));                                                    \
    PSUB((M) & 1, 1, meta0 + (M));                                                    \
    asm volatile("s_waitcnt lgkmcnt(0)" ::: "memory");                                \
    __builtin_amdgcn_s_barrier();                                                     \
    __builtin_amdgcn_sched_barrier(0);                                                \
    if (DOPF) stage((M) & 1, meta0 + (M) + 2);                                        \
} while (0)

template <int COLMODE>
__global__ __launch_bounds__(512, 4) void k_proj(const float* __restrict__ pair,
                                                 const s16* __restrict__ WT,
                                                 const float* __restrict__ bias,
                                                 s16* __restrict__ outT) {
    __shared__ __align__(16) float PA[2][32 * 128];  // 2 x 16KB fp32, swizzled
    const int t = threadIdx.x;
    const int w = t >> 6, l = t & 63;
    const int lr = l & 15, lg = l >> 4;
    const int d0 = w << 4;          // wave's h-stripe
    const int dl = d0 + (lg << 2);  // lane's h base
    const int rsw = lr & 7;
    // weights: loaded ONCE (16 VGPRs)
    s16x8 wv[4];
#pragma unroll
    for (int ks = 0; ks < 4; ++ks)
        wv[ks] = *(const s16x8*)(WT + (d0 + lr) * 128 + ks * 32 + lg * 8);
    const f32x4 b4 = *(const f32x4*)(bias + dl);
    const long meta0 = (long)blockIdx.x * 8;

    auto stage = [&](int buf, long meta) {
        {
            const int row = t >> 5, u = t & 31;
            const long gp = COLMODE ? (((meta & 15) * 32 + row) * 512 + (meta >> 4))
                                    : (meta * 32 + row);
            gload_lds16(pair + gp * 128 + ((u ^ (row & 7)) << 2),
                        (char*)&PA[buf][0] + t * 16);
        }
        {
            const int row = 16 + (t >> 5), u = t & 31;
            const long gp = COLMODE ? (((meta & 15) * 32 + row) * 512 + (meta >> 4))
                                    : (meta * 32 + row);
            gload_lds16(pair + gp * 128 + ((u ^ (row & 7)) << 2),
                        (char*)&PA[buf][0] + 8192 + t * 16);
        }
    };

    stage(0, meta0 + 0);
    stage(1, meta0 + 1);
    PITER(0, 2, 1);
    PITER(1, 2, 1);
    PITER(2, 2, 1);
    PITER(3, 2, 1);
    PITER(4, 2, 1);
    PITER(5, 2, 1);
    PITER(6, 2, 0);
    PITER(7, 0, 0);
}

// ---------------- K2 v2: triangle einsum, 256^2 tiles ----------------
// 8 waves (2M x 4N), per-wave 128x64 output, BK=64, LDS 64KB, 2 blocks/CU.
__global__ __launch_bounds__(512, 2) void k_tri(const s16* __restrict__ leftT,
                                                const s16* __restrict__ rightTT,
                                                s16* __restrict__ tri) {
    __shared__ __align__(16) s16 As[256 * 64];  // 32KB, u^(row&7) swizzled 16B units
    __shared__ __align__(16) s16 Bs[256 * 64];  // 32KB
    const int t = threadIdx.x;
    // 512 blocks = 128 h x 2 x 2; XCD-bijective (512 % 8 == 0), h-tiles XCD-contiguous
    const int logical = ((blockIdx.x & 7) << 6) | (blockIdx.x >> 3);
    const int h = logical >> 2;
    const int ti = (logical >> 1) & 1, tj = logical & 1;
    const s16* Ap = leftT + (long)h * NPOS + (long)ti * 256 * 512;
    const s16* Bp = rightTT + (long)h * NPOS + (long)tj * 256 * 512;
    const int w = t >> 6, l = t & 63;
    const int wr = (w >> 2) * 128, wc = (w & 3) * 64;
    const int lr = l & 15, lg = l >> 4;
    f32x4 acc[8][4];
#pragma unroll
    for (int mi = 0; mi < 8; ++mi)
#pragma unroll
        for (int ni = 0; ni < 4; ++ni) acc[mi][ni] = (f32x4){0.f, 0.f, 0.f, 0.f};
    for (int kb = 0; kb < 512; kb += 64) {
        __syncthreads();  // prior ds_reads done before DMA overwrite
#pragma unroll
        for (int P = 0; P < 4; ++P) {
            const int unit = P * 512 + t;          // 2048 16B units per matrix
            const int row = unit >> 3, u = unit & 7;
            const int kks = (u ^ (row & 7)) << 3;  // pre-swizzled source (involution)
            gload_lds16(Ap + (long)row * 512 + kb + kks, (char*)As + unit * 16);
            gload_lds16(Bp + (long)row * 512 + kb + kks, (char*)Bs + unit * 16);
        }
        __syncthreads();  // DMA landed
#pragma unroll
        for (int ks = 0; ks < 2; ++ks) {
            s16x8 af[8], bfv[4];
#pragma unroll
            for (int mi = 0; mi < 8; ++mi) {
                const int row = wr + mi * 16 + lr;
                af[mi] = *(const s16x8*)((const char*)As + row * 128 + (((ks * 4 + lg) ^ (row & 7)) << 4));
            }
#pragma unroll
            for (int ni = 0; ni < 4; ++ni) {
                const int row = wc + ni * 16 + lr;
                bfv[ni] = *(const s16x8*)((const char*)Bs + row * 128 + (((ks * 4 + lg) ^ (row & 7)) << 4));
            }
#pragma unroll
            for (int mi = 0; mi < 8; ++mi)
#pragma unroll
                for (int ni = 0; ni < 4; ++ni)
                    acc[mi][ni] = __builtin_amdgcn_mfma_f32_16x16x32_bf16(af[mi], bfv[ni], acc[mi][ni], 0, 0, 0);
        }
    }
#pragma unroll
    for (int mi = 0; mi < 8; ++mi) {
#pragma unroll
        for (int r = 0; r < 4; ++r) {
            const int i = ti * 256 + wr + mi * 16 + lg * 4 + r;
            s16* dst = tri + (long)h * NPOS + (long)i * 512 + tj * 256 + wc;
#pragma unroll
            for (int ni = 0; ni < 4; ++ni) dst[ni * 16 + lr] = f2bf(acc[mi][ni][r]);
        }
    }
}

// ---------------- K3 v11: C^T form + async LDS staging; in-LDS transpose of tri ----------------
// TRI slot layout: slot s holds tri[h = s>>2][pb + po*8 .. +8] with po = (s&3) ^ ((h>>3)&3).
#define SUBTILE(BUF, SUB) do {                                                        \
    const int row_ = (SUB) * 16 + lr;                                                 \
    const int po_ = row_ >> 3, p3_ = row_ & 7;                                        \
    const char* pbp_ = (const char*)&PA[BUF][0] + row_ * 512;                         \
    f32x4 accO_ = (f32x4){0.f, 0.f, 0.f, 0.f};                                        \
    f32x4 accG_ = (f32x4){0.f, 0.f, 0.f, 0.f};                                        \
    _Pragma("unroll")                                                                 \
    for (int ks = 0; ks < 4; ++ks) {                                                  \
        const int kk = ks * 32 + lg * 8;                                              \
        s16x8 tbv_;                                                                   \
        _Pragma("unroll")                                                             \
        for (int j = 0; j < 8; ++j) {                                                 \
            const int hh_ = kk + j;                                                   \
            tbv_[j] = TRI[BUF][(hh_ * 4 + (po_ ^ ((hh_ >> 3) & 3))) * 8 + p3_];       \
        }                                                                             \
        f32x4 pa0_ = *(const f32x4*)(pbp_ + ((((ks << 3) | (lg << 1)) ^ rsw) << 4));  \
        f32x4 pa1_ = *(const f32x4*)(pbp_ + (((((ks << 3) | (lg << 1)) + 1) ^ rsw) << 4)); \
        s16x8 pf_ = cvt8(pa0_, pa1_);                                                 \
        accO_ = __builtin_amdgcn_mfma_f32_16x16x32_bf16(wo[ks], tbv_, accO_, 0, 0, 0);\
        accG_ = __builtin_amdgcn_mfma_f32_16x16x32_bf16(wg[ks], pf_, accG_, 0, 0, 0); \
    }                                                                                 \
    f32x4 rs_ = *(const f32x4*)(pbp_ + ((((w << 2) | lg) ^ rsw) << 4));               \
    f32x4 xr_;                                                                        \
    _Pragma("unroll")                                                                 \
    for (int r = 0; r < 4; ++r) {                                                     \
        const float gate_ = 1.f / (1.f + __expf(-(accG_[r] + bg4[r])));               \
        xr_[r] = rs_[r] + gate_ * (accO_[r] + bo4[r]);                                \
    }                                                                                 \
    *(f32x4*)&xbuf[row_][dl] = xr_;                                                   \
} while (0)

#define LNPASS(P, META) do {                                                          \
    const int row_ = (P) * 16 + (t >> 5);                                             \
    f32x4 xv_ = *(const f32x4*)&xbuf[row_][lnc];                                      \
    float s_ = xv_[0] + xv_[1] + xv_[2] + xv_[3];                                     \
    s_ += __shfl_xor(s_, 1); s_ += __shfl_xor(s_, 2); s_ += __shfl_xor(s_, 4);        \
    s_ += __shfl_xor(s_, 8); s_ += __shfl_xor(s_, 16);                                \
    const float mu_ = s_ * 0.0078125f;                                                \
    float v_ = 0.f;                                                                   \
    _Pragma("unroll")                                                                 \
    for (int j = 0; j < 4; ++j) { float dd_ = xv_[j] - mu_; v_ += dd_ * dd_; }        \
    v_ += __shfl_xor(v_, 1); v_ += __shfl_xor(v_, 2); v_ += __shfl_xor(v_, 4);        \
    v_ += __shfl_xor(v_, 8); v_ += __shfl_xor(v_, 16);                                \
    const float rstd_ = rsqrtf(v_ * 0.0078125f + 1e-5f);                              \
    f32x4 o_;                                                                         \
    _Pragma("unroll")                                                                 \
    for (int j = 0; j < 4; ++j) o_[j] = (xv_[j] - mu_) * rstd_ * gm4[j] + bt4[j];     \
    *(f32x4*)(out + ((META) * 32 + row_) * 128 + lnc) = o_;                           \
} while (0)

#define ITER(M, NLIT, DOPF) do {                                                      \
    WAITVM(NLIT);                                                                     \
    __builtin_amdgcn_s_barrier();                                                     \
    SUBTILE((M) & 1, 0);                                                              \
    SUBTILE((M) & 1, 1);                                                              \
    asm volatile("s_waitcnt lgkmcnt(0)" ::: "memory");                                \
    __builtin_amdgcn_s_barrier();                                                     \
    __builtin_amdgcn_sched_barrier(0);                                                \
    if (DOPF) stage((M) & 1, meta0 + (M) + 2);                                        \
    LNPASS(0, meta0 + (M));                                                           \
    LNPASS(1, meta0 + (M));                                                           \
} while (0)

__global__ __launch_bounds__(512, 2) void k_final(const float* __restrict__ pair,
                                                  const s16* __restrict__ tri,
                                                  const s16* __restrict__ WgT,
                                                  const s16* __restrict__ WoT,
                                                  const float* __restrict__ bgv,
                                                  const float* __restrict__ bov,
                                                  const float* __restrict__ gam,
                                                  const float* __restrict__ bet,
                                                  float* __restrict__ out) {
    __shared__ __align__(16) s16 TRI[2][32 * 128];   // 2 x 8KB  (bf16, slot layout above)
    __shared__ __align__(16) float PA[2][32 * 128];  // 2 x 16KB (fp32 [pos][d], swizzled)
    __shared__ __align__(16) float xbuf[32][132];    // 16.9KB
    const int t = threadIdx.x;
    const int w = t >> 6, l = t & 63;
    const int lr = l & 15, lg = l >> 4;
    const int d0 = w << 4;             // wave's d-stripe
    const int dl = d0 + (lg << 2);     // lane's d base (epilogue rows)
    const int rsw = lr & 7;            // read-side swizzle key for PA
    // weights: loaded ONCE, A-operand of both GEMMs (32 VGPRs)
    s16x8 wo[4], wg[4];
#pragma unroll
    for (int ks = 0; ks < 4; ++ks) {
        wo[ks] = *(const s16x8*)(WoT + (d0 + lr) * 128 + ks * 32 + lg * 8);
        wg[ks] = *(const s16x8*)(WgT + (d0 + lr) * 128 + ks * 32 + lg * 8);
    }
    const f32x4 bo4 = *(const f32x4*)(bov + dl);
    const f32x4 bg4 = *(const f32x4*)(bgv + dl);
    const int lnc = (t & 31) << 2;     // LN: d chunk (f32x4)
    const f32x4 gm4 = *(const f32x4*)(gam + lnc);
    const f32x4 bt4 = *(const f32x4*)(bet + lnc);
    const long meta0 = (long)blockIdx.x * 8;

    // stage one 32-pos meta: 3 gload_lds16 per thread, linear LDS dest.
    auto stage = [&](int buf, long meta) {
        const long pb = meta * 32;
        {
            const int hh = t >> 2;
            const int po = (t & 3) ^ ((hh >> 3) & 3);
            gload_lds16(tri + (long)hh * NPOS + pb + po * 8,
                        (char*)&TRI[buf][0] + t * 16);
        }
        {
            const int row = t >> 5, u = t & 31;  // pair rows 0..15: 32 units x 16B
            gload_lds16(pair + (pb + row) * 128 + ((u ^ (row & 7)) << 2),
                        (char*)&PA[buf][0] + t * 16);
        }
        {
            const int row = 16 + (t >> 5), u = t & 31;  // pair rows 16..31
            gload_lds16(pair + (pb + row) * 128 + ((u ^ (row & 7)) << 2),
                        (char*)&PA[buf][0] + 8192 + t * 16);
        }
    };

    stage(0, meta0 + 0);
    stage(1, meta0 + 1);
    ITER(0, 3, 1);
    ITER(1, 3, 1);
    ITER(2, 3, 1);
    ITER(3, 3, 1);
    ITER(4, 3, 1);
    ITER(5, 3, 1);
    ITER(6, 3, 0);
    ITER(7, 0, 0);
}

extern "C" void kernel_launch(void* const* d_in, const int* in_sizes, int n_in,
                              void* d_out, int out_size, void* d_ws, size_t ws_size,
                              hipStream_t stream) {
    const float* pair = (const float*)d_in[0];
    const float* Wl   = (const float*)d_in[1];
    const float* bl   = (const float*)d_in[2];
    const float* Wr   = (const float*)d_in[3];
    const float* br   = (const float*)d_in[4];
    const float* Wo   = (const float*)d_in[5];
    const float* bo   = (const float*)d_in[6];
    const float* Wg   = (const float*)d_in[7];
    const float* bg   = (const float*)d_in[8];
    const float* gam  = (const float*)d_in[9];
    const float* bet  = (const float*)d_in[10];
    float* out = (float*)d_out;

    s16* WlT = (s16*)d_ws;
    s16* WrT = WlT + 128 * 128;
    s16* WgT = WrT + 128 * 128;
    s16* WoT = WgT + 128 * 128;
    s16* leftT   = WoT + 128 * 128;            // [128][NPOS] (dead after k_tri)
    s16* rightTT = leftT + (long)128 * NPOS;   // [128][NPOS]
    s16* tri     = rightTT + (long)128 * NPOS; // [128][NPOS]

    k_prep<<<4, 256, 0, stream>>>(Wl, Wr, Wg, Wo, WlT, WrT, WgT, WoT);
    k_proj<0><<<1024, 512, 0, stream>>>(pair, WlT, bl, leftT);
    k_proj<1><<<1024, 512, 0, stream>>>(pair, WrT, br, rightTT);
    k_tri<<<512, 512, 0, stream>>>(leftT, rightTT, tri);
    k_final<<<1024, 512, 0, stream>>>(pair, tri, WgT, WoT, bg, bo, gam, bet, out);
}

// Round 18
// 243.942 us; speedup vs baseline: 1.3670x; 1.0435x over previous
//
#include <hip/hip_runtime.h>
#include <hip/hip_bf16.h>

// TriangleMultiplication on MI355X (gfx950).
// Pipeline: k_prep ; k_proj v2 (C^T + async staging) ; k_tri v3 (256^2, double-buffered
//           counted-vmcnt pipeline) ; k_final v11 (C^T + async staging, in-LDS transpose).
// ws layout: WlT|WrT|WgT|WoT (4*32KB) + leftT (64MB) + rightTT (64MB) + tri (64MB)

#define LSZ 512
#define NPOS (LSZ * LSZ)  // 262144 positions

typedef short s16;
typedef __attribute__((ext_vector_type(4))) short s16x4;
typedef __attribute__((ext_vector_type(8))) short s16x8;
typedef __attribute__((ext_vector_type(4))) float f32x4;

typedef const __attribute__((address_space(1))) unsigned int* gas1;
typedef __attribute__((address_space(3))) unsigned int* las3;

static __device__ __forceinline__ s16 f2bf(float f) {
    unsigned int u = __builtin_bit_cast(unsigned int, f);
    u += 0x7FFFu + ((u >> 16) & 1u);
    return (s16)(u >> 16);
}

// packed RNE fp32->bf16 pair (emits v_cvt_pk_bf16_f32; same bits as f2bf)
static __device__ __forceinline__ unsigned pkbf(float x, float y) {
    __hip_bfloat162 h = __float22bfloat162_rn(make_float2(x, y));
    unsigned u;
    __builtin_memcpy(&u, &h, 4);
    return u;
}
static __device__ __forceinline__ s16x8 cvt8(f32x4 a, f32x4 b) {
    union { s16x8 v; unsigned u[4]; } r;
    r.u[0] = pkbf(a[0], a[1]);
    r.u[1] = pkbf(a[2], a[3]);
    r.u[2] = pkbf(b[0], b[1]);
    r.u[3] = pkbf(b[2], b[3]);
    return r.v;
}
static __device__ __forceinline__ s16x4 cvt4(float x0, float x1, float x2, float x3) {
    union { s16x4 v; unsigned u[2]; } r;
    r.u[0] = pkbf(x0, x1);
    r.u[1] = pkbf(x2, x3);
    return r.v;
}

static __device__ __forceinline__ void gload_lds16(const void* g, void* l) {
    __builtin_amdgcn_global_load_lds((gas1)g, (las3)l, 16, 0, 0);
}

#define WAITVM(N) asm volatile("s_waitcnt vmcnt(" #N ")" ::: "memory")

// ---------------- K0: transpose weights to bf16 [out][in] ----------------
__global__ void k_prep(const float* __restrict__ Wl, const float* __restrict__ Wr,
                       const float* __restrict__ Wg, const float* __restrict__ Wo,
                       s16* __restrict__ WlT, s16* __restrict__ WrT,
                       s16* __restrict__ WgT, s16* __restrict__ WoT) {
    const float* src;
    s16* dst;
    switch (blockIdx.x) {
        case 0: src = Wl; dst = WlT; break;
        case 1: src = Wr; dst = WrT; break;
        case 2: src = Wg; dst = WgT; break;
        default: src = Wo; dst = WoT; break;
    }
    for (int e = threadIdx.x; e < 128 * 128; e += blockDim.x) {
        int o = e >> 7, i = e & 127;
        dst[e] = f2bf(src[i * 128 + o]);  // WT[o][i] = W[i][o]
    }
}

// ---------------- K1 v2: projection GEMM, C^T form + async LDS staging ----------------
#define PSUB(BUF, SUB, META) do {                                                     \
    const int row_ = (SUB) * 16 + lr;                                                 \
    const char* pbp_ = (const char*)&PA[BUF][0] + row_ * 512;                         \
    f32x4 acc_ = (f32x4){0.f, 0.f, 0.f, 0.f};                                         \
    _Pragma("unroll")                                                                 \
    for (int ks = 0; ks < 4; ++ks) {                                                  \
        f32x4 pa0_ = *(const f32x4*)(pbp_ + ((((ks << 3) | (lg << 1)) ^ rsw) << 4));  \
        f32x4 pa1_ = *(const f32x4*)(pbp_ + (((((ks << 3) | (lg << 1)) + 1) ^ rsw) << 4)); \
        s16x8 pf_ = cvt8(pa0_, pa1_);                                                 \
        acc_ = __builtin_amdgcn_mfma_f32_16x16x32_bf16(wv[ks], pf_, acc_, 0, 0, 0);   \
    }                                                                                 \
    const long pbase_ = COLMODE ? ((long)((META) >> 4) * 512 + (((META) & 15) << 5) + row_) \
                                : ((long)(META) * 32 + row_);                         \
    _Pragma("unroll")                                                                 \
    for (int r = 0; r < 4; ++r)                                                       \
        outT[(long)(dl + r) * NPOS + pbase_] = f2bf(acc_[r] + b4[r]);                 \
} while (0)

#define PITER(M, NLIT, DOPF) do {                                                     \
    WAITVM(NLIT);                                                                     \
    __builtin_amdgcn_s_barrier();                                                     \
    PSUB((M) & 1, 0, meta0 + (M));                                                    \
    PSUB((M) & 1, 1, meta0 + (M));                                                    \
    asm volatile("s_waitcnt lgkmcnt(0)" ::: "memory");                                \
    __builtin_amdgcn_s_barrier();                                                     \
    __builtin_amdgcn_sched_barrier(0);                                                \
    if (DOPF) stage((M) & 1, meta0 + (M) + 2);                                        \
} while (0)

template <int COLMODE>
__global__ __launch_bounds__(512, 4) void k_proj(const float* __restrict__ pair,
                                                 const s16* __restrict__ WT,
                                                 const float* __restrict__ bias,
                                                 s16* __restrict__ outT) {
    __shared__ __align__(16) float PA[2][32 * 128];  // 2 x 16KB fp32, swizzled
    const int t = threadIdx.x;
    const int w = t >> 6, l = t & 63;
    const int lr = l & 15, lg = l >> 4;
    const int d0 = w << 4;          // wave's h-stripe
    const int dl = d0 + (lg << 2);  // lane's h base
    const int rsw = lr & 7;
    // weights: loaded ONCE (16 VGPRs)
    s16x8 wv[4];
#pragma unroll
    for (int ks = 0; ks < 4; ++ks)
        wv[ks] = *(const s16x8*)(WT + (d0 + lr) * 128 + ks * 32 + lg * 8);
    const f32x4 b4 = *(const f32x4*)(bias + dl);
    const long meta0 = (long)blockIdx.x * 8;

    auto stage = [&](int buf, long meta) {
        {
            const int row = t >> 5, u = t & 31;
            const long gp = COLMODE ? (((meta & 15) * 32 + row) * 512 + (meta >> 4))
                                    : (meta * 32 + row);
            gload_lds16(pair + gp * 128 + ((u ^ (row & 7)) << 2),
                        (char*)&PA[buf][0] + t * 16);
        }
        {
            const int row = 16 + (t >> 5), u = t & 31;
            const long gp = COLMODE ? (((meta & 15) * 32 + row) * 512 + (meta >> 4))
                                    : (meta * 32 + row);
            gload_lds16(pair + gp * 128 + ((u ^ (row & 7)) << 2),
                        (char*)&PA[buf][0] + 8192 + t * 16);
        }
    };

    stage(0, meta0 + 0);
    stage(1, meta0 + 1);
    PITER(0, 2, 1);
    PITER(1, 2, 1);
    PITER(2, 2, 1);
    PITER(3, 2, 1);
    PITER(4, 2, 1);
    PITER(5, 2, 1);
    PITER(6, 2, 0);
    PITER(7, 0, 0);
}

// ---------------- K2 v3: triangle einsum, 256^2 tiles, dbuf + counted vmcnt ----------------
// 8 waves (2M x 4N), per-wave 128x64, BK=64, double-buffered (128KB LDS, 1 block/CU).
// Per K-step: WAITVM(8) [16 outstanding - 8 current] -> barrier -> 64 MFMA/wave ->
// lgkmcnt(0) -> barrier -> stage(k+2) into just-consumed buffer. Never vmcnt(0) mid-loop.
__global__ __launch_bounds__(512, 1) void k_tri(const s16* __restrict__ leftT,
                                                const s16* __restrict__ rightTT,
                                                s16* __restrict__ tri) {
    __shared__ __align__(16) s16 As[2][256 * 64];  // 2 x 32KB, u^(row&7) swizzled
    __shared__ __align__(16) s16 Bs[2][256 * 64];  // 2 x 32KB
    const int t = threadIdx.x;
    // 512 blocks = 128 h x 2 x 2; XCD-bijective (512 % 8 == 0)
    const int logical = ((blockIdx.x & 7) << 6) | (blockIdx.x >> 3);
    const int h = logical >> 2;
    const int ti = (logical >> 1) & 1, tj = logical & 1;
    const s16* Ap = leftT + (long)h * NPOS + (long)ti * 256 * 512;
    const s16* Bp = rightTT + (long)h * NPOS + (long)tj * 256 * 512;
    const int w = t >> 6, l = t & 63;
    const int wr = (w >> 2) * 128, wc = (w & 3) * 64;
    const int lr = l & 15, lg = l >> 4;

    auto stage = [&](int buf, int kb) {
#pragma unroll
        for (int P = 0; P < 4; ++P) {
            const int unit = P * 512 + t;          // 2048 16B units per matrix
            const int row = unit >> 3, u = unit & 7;
            const int kks = (u ^ (row & 7)) << 3;  // pre-swizzled source (involution)
            gload_lds16(Ap + (long)row * 512 + kb + kks, (char*)&As[buf][0] + unit * 16);
            gload_lds16(Bp + (long)row * 512 + kb + kks, (char*)&Bs[buf][0] + unit * 16);
        }
    };

    f32x4 acc[8][4];
#pragma unroll
    for (int mi = 0; mi < 8; ++mi)
#pragma unroll
        for (int ni = 0; ni < 4; ++ni) acc[mi][ni] = (f32x4){0.f, 0.f, 0.f, 0.f};

    stage(0, 0);
    stage(1, 64);
#pragma unroll
    for (int k = 0; k < 8; ++k) {
        if (k < 7) { WAITVM(8); } else { WAITVM(0); }
        __builtin_amdgcn_s_barrier();
        const int buf = k & 1;
#pragma unroll
        for (int ks = 0; ks < 2; ++ks) {
            s16x8 af[8], bfv[4];
#pragma unroll
            for (int mi = 0; mi < 8; ++mi) {
                const int row = wr + mi * 16 + lr;
                af[mi] = *(const s16x8*)((const char*)&As[buf][0] + row * 128 + (((ks * 4 + lg) ^ (row & 7)) << 4));
            }
#pragma unroll
            for (int ni = 0; ni < 4; ++ni) {
                const int row = wc + ni * 16 + lr;
                bfv[ni] = *(const s16x8*)((const char*)&Bs[buf][0] + row * 128 + (((ks * 4 + lg) ^ (row & 7)) << 4));
            }
#pragma unroll
            for (int mi = 0; mi < 8; ++mi)
#pragma unroll
                for (int ni = 0; ni < 4; ++ni)
                    acc[mi][ni] = __builtin_amdgcn_mfma_f32_16x16x32_bf16(af[mi], bfv[ni], acc[mi][ni], 0, 0, 0);
        }
        asm volatile("s_waitcnt lgkmcnt(0)" ::: "memory");
        __builtin_amdgcn_s_barrier();
        __builtin_amdgcn_sched_barrier(0);
        if (k + 2 < 8) stage(buf, (k + 2) * 64);
    }
#pragma unroll
    for (int mi = 0; mi < 8; ++mi) {
#pragma unroll
        for (int r = 0; r < 4; ++r) {
            const int i = ti * 256 + wr + mi * 16 + lg * 4 + r;
            s16* dst = tri + (long)h * NPOS + (long)i * 512 + tj * 256 + wc;
#pragma unroll
            for (int ni = 0; ni < 4; ++ni) dst[ni * 16 + lr] = f2bf(acc[mi][ni][r]);
        }
    }
}

// ---------------- K3 v11: C^T form + async LDS staging; in-LDS transpose of tri ----------------
// TRI slot layout: slot s holds tri[h = s>>2][pb + po*8 .. +8] with po = (s&3) ^ ((h>>3)&3).
#define SUBTILE(BUF, SUB) do {                                                        \
    const int row_ = (SUB) * 16 + lr;                                                 \
    const int po_ = row_ >> 3, p3_ = row_ & 7;                                        \
    const char* pbp_ = (const char*)&PA[BUF][0] + row_ * 512;                         \
    f32x4 accO_ = (f32x4){0.f, 0.f, 0.f, 0.f};                                        \
    f32x4 accG_ = (f32x4){0.f, 0.f, 0.f, 0.f};                                        \
    _Pragma("unroll")                                                                 \
    for (int ks = 0; ks < 4; ++ks) {                                                  \
        const int kk = ks * 32 + lg * 8;                                              \
        s16x8 tbv_;                                                                   \
        _Pragma("unroll")                                                             \
        for (int j = 0; j < 8; ++j) {                                                 \
            const int hh_ = kk + j;                                                   \
            tbv_[j] = TRI[BUF][(hh_ * 4 + (po_ ^ ((hh_ >> 3) & 3))) * 8 + p3_];       \
        }                                                                             \
        f32x4 pa0_ = *(const f32x4*)(pbp_ + ((((ks << 3) | (lg << 1)) ^ rsw) << 4));  \
        f32x4 pa1_ = *(const f32x4*)(pbp_ + (((((ks << 3) | (lg << 1)) + 1) ^ rsw) << 4)); \
        s16x8 pf_ = cvt8(pa0_, pa1_);                                                 \
        accO_ = __builtin_amdgcn_mfma_f32_16x16x32_bf16(wo[ks], tbv_, accO_, 0, 0, 0);\
        accG_ = __builtin_amdgcn_mfma_f32_16x16x32_bf16(wg[ks], pf_, accG_, 0, 0, 0); \
    }                                                                                 \
    f32x4 rs_ = *(const f32x4*)(pbp_ + ((((w << 2) | lg) ^ rsw) << 4));               \
    f32x4 xr_;                                                                        \
    _Pragma("unroll")                                                                 \
    for (int r = 0; r < 4; ++r) {                                                     \
        const float gate_ = 1.f / (1.f + __expf(-(accG_[r] + bg4[r])));               \
        xr_[r] = rs_[r] + gate_ * (accO_[r] + bo4[r]);                                \
    }                                                                                 \
    *(f32x4*)&xbuf[row_][dl] = xr_;                                                   \
} while (0)

#define LNPASS(P, META) do {                                                          \
    const int row_ = (P) * 16 + (t >> 5);                                             \
    f32x4 xv_ = *(const f32x4*)&xbuf[row_][lnc];                                      \
    float s_ = xv_[0] + xv_[1] + xv_[2] + xv_[3];                                     \
    s_ += __shfl_xor(s_, 1); s_ += __shfl_xor(s_, 2); s_ += __shfl_xor(s_, 4);        \
    s_ += __shfl_xor(s_, 8); s_ += __shfl_xor(s_, 16);                                \
    const float mu_ = s_ * 0.0078125f;                                                \
    float v_ = 0.f;                                                                   \
    _Pragma("unroll")                                                                 \
    for (int j = 0; j < 4; ++j) { float dd_ = xv_[j] - mu_; v_ += dd_ * dd_; }        \
    v_ += __shfl_xor(v_, 1); v_ += __shfl_xor(v_, 2); v_ += __shfl_xor(v_, 4);        \
    v_ += __shfl_xor(v_, 8); v_ += __shfl_xor(v_, 16);                                \
    const float rstd_ = rsqrtf(v_ * 0.0078125f + 1e-5f);                              \
    f32x4 o_;                                                                         \
    _Pragma("unroll")                                                                 \
    for (int j = 0; j < 4; ++j) o_[j] = (xv_[j] - mu_) * rstd_ * gm4[j] + bt4[j];     \
    *(f32x4*)(out + ((META) * 32 + row_) * 128 + lnc) = o_;                           \
} while (0)

#define ITER(M, NLIT, DOPF) do {                                                      \
    WAITVM(NLIT);                                                                     \
    __builtin_amdgcn_s_barrier();                                                     \
    SUBTILE((M) & 1, 0);                                                              \
    SUBTILE((M) & 1, 1);                                                              \
    asm volatile("s_waitcnt lgkmcnt(0)" ::: "memory");                                \
    __builtin_amdgcn_s_barrier();                                                     \
    __builtin_amdgcn_sched_barrier(0);                                                \
    if (DOPF) stage((M) & 1, meta0 + (M) + 2);                                        \
    LNPASS(0, meta0 + (M));                                                           \
    LNPASS(1, meta0 + (M));                                                           \
} while (0)

__global__ __launch_bounds__(512, 2) void k_final(const float* __restrict__ pair,
                                                  const s16* __restrict__ tri,
                                                  const s16* __restrict__ WgT,
                                                  const s16* __restrict__ WoT,
                                                  const float* __restrict__ bgv,
                                                  const float* __restrict__ bov,
                                                  const float* __restrict__ gam,
                                                  const float* __restrict__ bet,
                                                  float* __restrict__ out) {
    __shared__ __align__(16) s16 TRI[2][32 * 128];   // 2 x 8KB  (bf16, slot layout above)
    __shared__ __align__(16) float PA[2][32 * 128];  // 2 x 16KB (fp32 [pos][d], swizzled)
    __shared__ __align__(16) float xbuf[32][132];    // 16.9KB
    const int t = threadIdx.x;
    const int w = t >> 6, l = t & 63;
    const int lr = l & 15, lg = l >> 4;
    const int d0 = w << 4;             // wave's d-stripe
    const int dl = d0 + (lg << 2);     // lane's d base (epilogue rows)
    const int rsw = lr & 7;            // read-side swizzle key for PA
    // weights: loaded ONCE, A-operand of both GEMMs (32 VGPRs)
    s16x8 wo[4], wg[4];
#pragma unroll
    for (int ks = 0; ks < 4; ++ks) {
        wo[ks] = *(const s16x8*)(WoT + (d0 + lr) * 128 + ks * 32 + lg * 8);
        wg[ks] = *(const s16x8*)(WgT + (d0 + lr) * 128 + ks * 32 + lg * 8);
    }
    const f32x4 bo4 = *(const f32x4*)(bov + dl);
    const f32x4 bg4 = *(const f32x4*)(bgv + dl);
    const int lnc = (t & 31) << 2;     // LN: d chunk (f32x4)
    const f32x4 gm4 = *(const f32x4*)(gam + lnc);
    const f32x4 bt4 = *(const f32x4*)(bet + lnc);
    const long meta0 = (long)blockIdx.x * 8;

    // stage one 32-pos meta: 3 gload_lds16 per thread, linear LDS dest.
    auto stage = [&](int buf, long meta) {
        const long pb = meta * 32;
        {
            const int hh = t >> 2;
            const int po = (t & 3) ^ ((hh >> 3) & 3);
            gload_lds16(tri + (long)hh * NPOS + pb + po * 8,
                        (char*)&TRI[buf][0] + t * 16);
        }
        {
            const int row = t >> 5, u = t & 31;  // pair rows 0..15: 32 units x 16B
            gload_lds16(pair + (pb + row) * 128 + ((u ^ (row & 7)) << 2),
                        (char*)&PA[buf][0] + t * 16);
        }
        {
            const int row = 16 + (t >> 5), u = t & 31;  // pair rows 16..31
            gload_lds16(pair + (pb + row) * 128 + ((u ^ (row & 7)) << 2),
                        (char*)&PA[buf][0] + 8192 + t * 16);
        }
    };

    stage(0, meta0 + 0);
    stage(1, meta0 + 1);
    ITER(0, 3, 1);
    ITER(1, 3, 1);
    ITER(2, 3, 1);
    ITER(3, 3, 1);
    ITER(4, 3, 1);
    ITER(5, 3, 1);
    ITER(6, 3, 0);
    ITER(7, 0, 0);
}

extern "C" void kernel_launch(void* const* d_in, const int* in_sizes, int n_in,
                              void* d_out, int out_size, void* d_ws, size_t ws_size,
                              hipStream_t stream) {
    const float* pair = (const float*)d_in[0];
    const float* Wl   = (const float*)d_in[1];
    const float* bl   = (const float*)d_in[2];
    const float* Wr   = (const float*)d_in[3];
    const float* br   = (const float*)d_in[4];
    const float* Wo   = (const float*)d_in[5];
    const float* bo   = (const float*)d_in[6];
    const float* Wg   = (const float*)d_in[7];
    const float* bg   = (const float*)d_in[8];
    const float* gam  = (const float*)d_in[9];
    const float* bet  = (const float*)d_in[10];
    float* out = (float*)d_out;

    s16* WlT = (s16*)d_ws;
    s16* WrT = WlT + 128 * 128;
    s16* WgT = WrT + 128 * 128;
    s16* WoT = WgT + 128 * 128;
    s16* leftT   = WoT + 128 * 128;            // [128][NPOS] (dead after k_tri)
    s16* rightTT = leftT + (long)128 * NPOS;   // [128][NPOS]
    s16* tri     = rightTT + (long)128 * NPOS; // [128][NPOS]

    k_prep<<<4, 256, 0, stream>>>(Wl, Wr, Wg, Wo, WlT, WrT, WgT, WoT);
    k_proj<0><<<1024, 512, 0, stream>>>(pair, WlT, bl, leftT);
    k_proj<1><<<1024, 512, 0, stream>>>(pair, WrT, br, rightTT);
    k_tri<<<512, 512, 0, stream>>>(leftT, rightTT, tri);
    k_final<<<1024, 512, 0, stream>>>(pair, tri, WgT, WoT, bg, bo, gam, bet, out);
}

// Round 19
// 240.714 us; speedup vs baseline: 1.3854x; 1.0134x over previous
//
#include <hip/hip_runtime.h>
#include <hip/hip_bf16.h>

// TriangleMultiplication on MI355X (gfx950).
// Pipeline: k_prep ; k_proj v2 (C^T + async staging) ; k_tri v3 (256^2, dbuf counted-vmcnt) ;
//           k_final v12 (C^T + async staging, in-LDS transpose; xbuf stride 140, nt stores).
// ws layout: WlT|WrT|WgT|WoT (4*32KB) + leftT (64MB) + rightTT (64MB) + tri (64MB)

#define LSZ 512
#define NPOS (LSZ * LSZ)  // 262144 positions

typedef short s16;
typedef __attribute__((ext_vector_type(4))) short s16x4;
typedef __attribute__((ext_vector_type(8))) short s16x8;
typedef __attribute__((ext_vector_type(4))) float f32x4;

typedef const __attribute__((address_space(1))) unsigned int* gas1;
typedef __attribute__((address_space(3))) unsigned int* las3;

static __device__ __forceinline__ s16 f2bf(float f) {
    unsigned int u = __builtin_bit_cast(unsigned int, f);
    u += 0x7FFFu + ((u >> 16) & 1u);
    return (s16)(u >> 16);
}

// packed RNE fp32->bf16 pair (emits v_cvt_pk_bf16_f32; same bits as f2bf)
static __device__ __forceinline__ unsigned pkbf(float x, float y) {
    __hip_bfloat162 h = __float22bfloat162_rn(make_float2(x, y));
    unsigned u;
    __builtin_memcpy(&u, &h, 4);
    return u;
}
static __device__ __forceinline__ s16x8 cvt8(f32x4 a, f32x4 b) {
    union { s16x8 v; unsigned u[4]; } r;
    r.u[0] = pkbf(a[0], a[1]);
    r.u[1] = pkbf(a[2], a[3]);
    r.u[2] = pkbf(b[0], b[1]);
    r.u[3] = pkbf(b[2], b[3]);
    return r.v;
}
static __device__ __forceinline__ s16x4 cvt4(float x0, float x1, float x2, float x3) {
    union { s16x4 v; unsigned u[2]; } r;
    r.u[0] = pkbf(x0, x1);
    r.u[1] = pkbf(x2, x3);
    return r.v;
}

static __device__ __forceinline__ void gload_lds16(const void* g, void* l) {
    __builtin_amdgcn_global_load_lds((gas1)g, (las3)l, 16, 0, 0);
}

#define WAITVM(N) asm volatile("s_waitcnt vmcnt(" #N ")" ::: "memory")

// ---------------- K0: transpose weights to bf16 [out][in] ----------------
__global__ void k_prep(const float* __restrict__ Wl, const float* __restrict__ Wr,
                       const float* __restrict__ Wg, const float* __restrict__ Wo,
                       s16* __restrict__ WlT, s16* __restrict__ WrT,
                       s16* __restrict__ WgT, s16* __restrict__ WoT) {
    const float* src;
    s16* dst;
    switch (blockIdx.x) {
        case 0: src = Wl; dst = WlT; break;
        case 1: src = Wr; dst = WrT; break;
        case 2: src = Wg; dst = WgT; break;
        default: src = Wo; dst = WoT; break;
    }
    for (int e = threadIdx.x; e < 128 * 128; e += blockDim.x) {
        int o = e >> 7, i = e & 127;
        dst[e] = f2bf(src[i * 128 + o]);  // WT[o][i] = W[i][o]
    }
}

// ---------------- K1 v2: projection GEMM, C^T form + async LDS staging ----------------
#define PSUB(BUF, SUB, META) do {                                                     \
    const int row_ = (SUB) * 16 + lr;                                                 \
    const char* pbp_ = (const char*)&PA[BUF][0] + row_ * 512;                         \
    f32x4 acc_ = (f32x4){0.f, 0.f, 0.f, 0.f};                                         \
    _Pragma("unroll")                                                                 \
    for (int ks = 0; ks < 4; ++ks) {                                                  \
        f32x4 pa0_ = *(const f32x4*)(pbp_ + ((((ks << 3) | (lg << 1)) ^ rsw) << 4));  \
        f32x4 pa1_ = *(const f32x4*)(pbp_ + (((((ks << 3) | (lg << 1)) + 1) ^ rsw) << 4)); \
        s16x8 pf_ = cvt8(pa0_, pa1_);                                                 \
        acc_ = __builtin_amdgcn_mfma_f32_16x16x32_bf16(wv[ks], pf_, acc_, 0, 0, 0);   \
    }                                                                                 \
    const long pbase_ = COLMODE ? ((long)((META) >> 4) * 512 + (((META) & 15) << 5) + row_) \
                                : ((long)(META) * 32 + row_);                         \
    _Pragma("unroll")                                                                 \
    for (int r = 0; r < 4; ++r)                                                       \
        outT[(long)(dl + r) * NPOS + pbase_] = f2bf(acc_[r] + b4[r]);                 \
} while (0)

#define PITER(M, NLIT, DOPF) do {                                                     \
    WAITVM(NLIT);                                                                     \
    __builtin_amdgcn_s_barrier();                                                     \
    PSUB((M) & 1, 0, meta0 + (M));                                                    \
    PSUB((M) & 1, 1, meta0 + (M));                                                    \
    asm volatile("s_waitcnt lgkmcnt(0)" ::: "memory");                                \
    __builtin_amdgcn_s_barrier();                                                     \
    __builtin_amdgcn_sched_barrier(0);                                                \
    if (DOPF) stage((M) & 1, meta0 + (M) + 2);                                        \
} while (0)

template <int COLMODE>
__global__ __launch_bounds__(512, 4) void k_proj(const float* __restrict__ pair,
                                                 const s16* __restrict__ WT,
                                                 const float* __restrict__ bias,
                                                 s16* __restrict__ outT) {
    __shared__ __align__(16) float PA[2][32 * 128];  // 2 x 16KB fp32, swizzled
    const int t = threadIdx.x;
    const int w = t >> 6, l = t & 63;
    const int lr = l & 15, lg = l >> 4;
    const int d0 = w << 4;          // wave's h-stripe
    const int dl = d0 + (lg << 2);  // lane's h base
    const int rsw = lr & 7;
    // weights: loaded ONCE (16 VGPRs)
    s16x8 wv[4];
#pragma unroll
    for (int ks = 0; ks < 4; ++ks)
        wv[ks] = *(const s16x8*)(WT + (d0 + lr) * 128 + ks * 32 + lg * 8);
    const f32x4 b4 = *(const f32x4*)(bias + dl);
    const long meta0 = (long)blockIdx.x * 8;

    auto stage = [&](int buf, long meta) {
        {
            const int row = t >> 5, u = t & 31;
            const long gp = COLMODE ? (((meta & 15) * 32 + row) * 512 + (meta >> 4))
                                    : (meta * 32 + row);
            gload_lds16(pair + gp * 128 + ((u ^ (row & 7)) << 2),
                        (char*)&PA[buf][0] + t * 16);
        }
        {
            const int row = 16 + (t >> 5), u = t & 31;
            const long gp = COLMODE ? (((meta & 15) * 32 + row) * 512 + (meta >> 4))
                                    : (meta * 32 + row);
            gload_lds16(pair + gp * 128 + ((u ^ (row & 7)) << 2),
                        (char*)&PA[buf][0] + 8192 + t * 16);
        }
    };

    stage(0, meta0 + 0);
    stage(1, meta0 + 1);
    PITER(0, 2, 1);
    PITER(1, 2, 1);
    PITER(2, 2, 1);
    PITER(3, 2, 1);
    PITER(4, 2, 1);
    PITER(5, 2, 1);
    PITER(6, 2, 0);
    PITER(7, 0, 0);
}

// ---------------- K2 v3: triangle einsum, 256^2 tiles, dbuf + counted vmcnt ----------------
__global__ __launch_bounds__(512, 1) void k_tri(const s16* __restrict__ leftT,
                                                const s16* __restrict__ rightTT,
                                                s16* __restrict__ tri) {
    __shared__ __align__(16) s16 As[2][256 * 64];  // 2 x 32KB, u^(row&7) swizzled
    __shared__ __align__(16) s16 Bs[2][256 * 64];  // 2 x 32KB
    const int t = threadIdx.x;
    const int logical = ((blockIdx.x & 7) << 6) | (blockIdx.x >> 3);
    const int h = logical >> 2;
    const int ti = (logical >> 1) & 1, tj = logical & 1;
    const s16* Ap = leftT + (long)h * NPOS + (long)ti * 256 * 512;
    const s16* Bp = rightTT + (long)h * NPOS + (long)tj * 256 * 512;
    const int w = t >> 6, l = t & 63;
    const int wr = (w >> 2) * 128, wc = (w & 3) * 64;
    const int lr = l & 15, lg = l >> 4;

    auto stage = [&](int buf, int kb) {
#pragma unroll
        for (int P = 0; P < 4; ++P) {
            const int unit = P * 512 + t;
            const int row = unit >> 3, u = unit & 7;
            const int kks = (u ^ (row & 7)) << 3;
            gload_lds16(Ap + (long)row * 512 + kb + kks, (char*)&As[buf][0] + unit * 16);
            gload_lds16(Bp + (long)row * 512 + kb + kks, (char*)&Bs[buf][0] + unit * 16);
        }
    };

    f32x4 acc[8][4];
#pragma unroll
    for (int mi = 0; mi < 8; ++mi)
#pragma unroll
        for (int ni = 0; ni < 4; ++ni) acc[mi][ni] = (f32x4){0.f, 0.f, 0.f, 0.f};

    stage(0, 0);
    stage(1, 64);
#pragma unroll
    for (int k = 0; k < 8; ++k) {
        if (k < 7) { WAITVM(8); } else { WAITVM(0); }
        __builtin_amdgcn_s_barrier();
        const int buf = k & 1;
#pragma unroll
        for (int ks = 0; ks < 2; ++ks) {
            s16x8 af[8], bfv[4];
#pragma unroll
            for (int mi = 0; mi < 8; ++mi) {
                const int row = wr + mi * 16 + lr;
                af[mi] = *(const s16x8*)((const char*)&As[buf][0] + row * 128 + (((ks * 4 + lg) ^ (row & 7)) << 4));
            }
#pragma unroll
            for (int ni = 0; ni < 4; ++ni) {
                const int row = wc + ni * 16 + lr;
                bfv[ni] = *(const s16x8*)((const char*)&Bs[buf][0] + row * 128 + (((ks * 4 + lg) ^ (row & 7)) << 4));
            }
#pragma unroll
            for (int mi = 0; mi < 8; ++mi)
#pragma unroll
                for (int ni = 0; ni < 4; ++ni)
                    acc[mi][ni] = __builtin_amdgcn_mfma_f32_16x16x32_bf16(af[mi], bfv[ni], acc[mi][ni], 0, 0, 0);
        }
        asm volatile("s_waitcnt lgkmcnt(0)" ::: "memory");
        __builtin_amdgcn_s_barrier();
        __builtin_amdgcn_sched_barrier(0);
        if (k + 2 < 8) stage(buf, (k + 2) * 64);
    }
#pragma unroll
    for (int mi = 0; mi < 8; ++mi) {
#pragma unroll
        for (int r = 0; r < 4; ++r) {
            const int i = ti * 256 + wr + mi * 16 + lg * 4 + r;
            s16* dst = tri + (long)h * NPOS + (long)i * 512 + tj * 256 + wc;
#pragma unroll
            for (int ni = 0; ni < 4; ++ni) dst[ni * 16 + lr] = f2bf(acc[mi][ni][r]);
        }
    }
}

// ---------------- K3 v12: C^T form + async staging; in-LDS transpose of tri ----------------
// xbuf stride 140 words (row shift = 12 banks; 8 rows cover all eight 4-word groups
// -> 16-lane f32x4 writes are ~2-way = free). out stores are non-temporal.
#define XST 140
#define SUBTILE(BUF, SUB) do {                                                        \
    const int row_ = (SUB) * 16 + lr;                                                 \
    const int po_ = row_ >> 3, p3_ = row_ & 7;                                        \
    const char* pbp_ = (const char*)&PA[BUF][0] + row_ * 512;                         \
    f32x4 accO_ = (f32x4){0.f, 0.f, 0.f, 0.f};                                        \
    f32x4 accG_ = (f32x4){0.f, 0.f, 0.f, 0.f};                                        \
    _Pragma("unroll")                                                                 \
    for (int ks = 0; ks < 4; ++ks) {                                                  \
        const int kk = ks * 32 + lg * 8;                                              \
        s16x8 tbv_;                                                                   \
        _Pragma("unroll")                                                             \
        for (int j = 0; j < 8; ++j) {                                                 \
            const int hh_ = kk + j;                                                   \
            tbv_[j] = TRI[BUF][(hh_ * 4 + (po_ ^ ((hh_ >> 3) & 3))) * 8 + p3_];       \
        }                                                                             \
        f32x4 pa0_ = *(const f32x4*)(pbp_ + ((((ks << 3) | (lg << 1)) ^ rsw) << 4));  \
        f32x4 pa1_ = *(const f32x4*)(pbp_ + (((((ks << 3) | (lg << 1)) + 1) ^ rsw) << 4)); \
        s16x8 pf_ = cvt8(pa0_, pa1_);                                                 \
        accO_ = __builtin_amdgcn_mfma_f32_16x16x32_bf16(wo[ks], tbv_, accO_, 0, 0, 0);\
        accG_ = __builtin_amdgcn_mfma_f32_16x16x32_bf16(wg[ks], pf_, accG_, 0, 0, 0); \
    }                                                                                 \
    f32x4 rs_ = *(const f32x4*)(pbp_ + ((((w << 2) | lg) ^ rsw) << 4));               \
    f32x4 xr_;                                                                        \
    _Pragma("unroll")                                                                 \
    for (int r = 0; r < 4; ++r) {                                                     \
        const float gate_ = 1.f / (1.f + __expf(-(accG_[r] + bg4[r])));               \
        xr_[r] = rs_[r] + gate_ * (accO_[r] + bo4[r]);                                \
    }                                                                                 \
    *(f32x4*)&xbuf[row_ * XST + dl] = xr_;                                            \
} while (0)

#define LNPASS(P, META) do {                                                          \
    const int row_ = (P) * 16 + (t >> 5);                                             \
    f32x4 xv_ = *(const f32x4*)&xbuf[row_ * XST + lnc];                               \
    float s_ = xv_[0] + xv_[1] + xv_[2] + xv_[3];                                     \
    s_ += __shfl_xor(s_, 1); s_ += __shfl_xor(s_, 2); s_ += __shfl_xor(s_, 4);        \
    s_ += __shfl_xor(s_, 8); s_ += __shfl_xor(s_, 16);                                \
    const float mu_ = s_ * 0.0078125f;                                                \
    float v_ = 0.f;                                                                   \
    _Pragma("unroll")                                                                 \
    for (int j = 0; j < 4; ++j) { float dd_ = xv_[j] - mu_; v_ += dd_ * dd_; }        \
    v_ += __shfl_xor(v_, 1); v_ += __shfl_xor(v_, 2); v_ += __shfl_xor(v_, 4);        \
    v_ += __shfl_xor(v_, 8); v_ += __shfl_xor(v_, 16);                                \
    const float rstd_ = rsqrtf(v_ * 0.0078125f + 1e-5f);                              \
    f32x4 o_;                                                                         \
    _Pragma("unroll")                                                                 \
    for (int j = 0; j < 4; ++j) o_[j] = (xv_[j] - mu_) * rstd_ * gm4[j] + bt4[j];     \
    __builtin_nontemporal_store(o_, (f32x4*)(out + ((META) * 32 + row_) * 128 + lnc));\
} while (0)

#define ITER(M, NLIT, DOPF) do {                                                      \
    WAITVM(NLIT);                                                                     \
    __builtin_amdgcn_s_barrier();                                                     \
    SUBTILE((M) & 1, 0);                                                              \
    SUBTILE((M) & 1, 1);                                                              \
    asm volatile("s_waitcnt lgkmcnt(0)" ::: "memory");                                \
    __builtin_amdgcn_s_barrier();                                                     \
    __builtin_amdgcn_sched_barrier(0);                                                \
    if (DOPF) stage((M) & 1, meta0 + (M) + 2);                                        \
    LNPASS(0, meta0 + (M));                                                           \
    LNPASS(1, meta0 + (M));                                                           \
} while (0)

__global__ __launch_bounds__(512, 2) void k_final(const float* __restrict__ pair,
                                                  const s16* __restrict__ tri,
                                                  const s16* __restrict__ WgT,
                                                  const s16* __restrict__ WoT,
                                                  const float* __restrict__ bgv,
                                                  const float* __restrict__ bov,
                                                  const float* __restrict__ gam,
                                                  const float* __restrict__ bet,
                                                  float* __restrict__ out) {
    __shared__ __align__(16) s16 TRI[2][32 * 128];   // 2 x 8KB  (bf16, slot layout)
    __shared__ __align__(16) float PA[2][32 * 128];  // 2 x 16KB (fp32 [pos][d], swizzled)
    __shared__ __align__(16) float xbuf[32 * XST];   // 17.9KB, stride 140
    const int t = threadIdx.x;
    const int w = t >> 6, l = t & 63;
    const int lr = l & 15, lg = l >> 4;
    const int d0 = w << 4;             // wave's d-stripe
    const int dl = d0 + (lg << 2);     // lane's d base (epilogue rows)
    const int rsw = lr & 7;            // read-side swizzle key for PA
    // weights: loaded ONCE, A-operand of both GEMMs (32 VGPRs)
    s16x8 wo[4], wg[4];
#pragma unroll
    for (int ks = 0; ks < 4; ++ks) {
        wo[ks] = *(const s16x8*)(WoT + (d0 + lr) * 128 + ks * 32 + lg * 8);
        wg[ks] = *(const s16x8*)(WgT + (d0 + lr) * 128 + ks * 32 + lg * 8);
    }
    const f32x4 bo4 = *(const f32x4*)(bov + dl);
    const f32x4 bg4 = *(const f32x4*)(bgv + dl);
    const int lnc = (t & 31) << 2;     // LN: d chunk (f32x4)
    const f32x4 gm4 = *(const f32x4*)(gam + lnc);
    const f32x4 bt4 = *(const f32x4*)(bet + lnc);
    const long meta0 = (long)blockIdx.x * 8;

    // stage one 32-pos meta: 3 gload_lds16 per thread, linear LDS dest.
    auto stage = [&](int buf, long meta) {
        const long pb = meta * 32;
        {
            const int hh = t >> 2;
            const int po = (t & 3) ^ ((hh >> 3) & 3);
            gload_lds16(tri + (long)hh * NPOS + pb + po * 8,
                        (char*)&TRI[buf][0] + t * 16);
        }
        {
            const int row = t >> 5, u = t & 31;  // pair rows 0..15
            gload_lds16(pair + (pb + row) * 128 + ((u ^ (row & 7)) << 2),
                        (char*)&PA[buf][0] + t * 16);
        }
        {
            const int row = 16 + (t >> 5), u = t & 31;  // pair rows 16..31
            gload_lds16(pair + (pb + row) * 128 + ((u ^ (row & 7)) << 2),
                        (char*)&PA[buf][0] + 8192 + t * 16);
        }
    };

    stage(0, meta0 + 0);
    stage(1, meta0 + 1);
    ITER(0, 3, 1);
    ITER(1, 3, 1);
    ITER(2, 3, 1);
    ITER(3, 3, 1);
    ITER(4, 3, 1);
    ITER(5, 3, 1);
    ITER(6, 3, 0);
    ITER(7, 0, 0);
}

extern "C" void kernel_launch(void* const* d_in, const int* in_sizes, int n_in,
                              void* d_out, int out_size, void* d_ws, size_t ws_size,
                              hipStream_t stream) {
    const float* pair = (const float*)d_in[0];
    const float* Wl   = (const float*)d_in[1];
    const float* bl   = (const float*)d_in[2];
    const float* Wr   = (const float*)d_in[3];
    const float* br   = (const float*)d_in[4];
    const float* Wo   = (const float*)d_in[5];
    const float* bo   = (const float*)d_in[6];
    const float* Wg   = (const float*)d_in[7];
    const float* bg   = (const float*)d_in[8];
    const float* gam  = (const float*)d_in[9];
    const float* bet  = (const float*)d_in[10];
    float* out = (float*)d_out;

    s16* WlT = (s16*)d_ws;
    s16* WrT = WlT + 128 * 128;
    s16* WgT = WrT + 128 * 128;
    s16* WoT = WgT + 128 * 128;
    s16* leftT   = WoT + 128 * 128;            // [128][NPOS] (dead after k_tri)
    s16* rightTT = leftT + (long)128 * NPOS;   // [128][NPOS]
    s16* tri     = rightTT + (long)128 * NPOS; // [128][NPOS]

    k_prep<<<4, 256, 0, stream>>>(Wl, Wr, Wg, Wo, WlT, WrT, WgT, WoT);
    k_proj<0><<<1024, 512, 0, stream>>>(pair, WlT, bl, leftT);
    k_proj<1><<<1024, 512, 0, stream>>>(pair, WrT, br, rightTT);
    k_tri<<<512, 512, 0, stream>>>(leftT, rightTT, tri);
    k_final<<<1024, 512, 0, stream>>>(pair, tri, WgT, WoT, bg, bo, gam, bet, out);
}